// Round 4
// baseline (208.054 us; speedup 1.0000x reference)
//
#include <hip/hip_runtime.h>

typedef __attribute__((ext_vector_type(8))) short s16x8;
typedef __attribute__((ext_vector_type(4))) float f32x4;

__device__ inline float bf2f(ushort u) {
    union { unsigned int i; float f; } v; v.i = ((unsigned)u) << 16; return v.f;
}
__device__ inline ushort f2bf(float f) {
    union { float f; unsigned int i; } v; v.f = f;
    unsigned r = v.i + 0x7FFFu + ((v.i >> 16) & 1u);
    return (ushort)(r >> 16);
}
__device__ inline unsigned pack2(float a, float b) {
    return (unsigned)f2bf(a) | ((unsigned)f2bf(b) << 16);
}
__device__ inline float silu_f(float x) { return x / (1.f + __expf(-x)); }

// K1: x = node_features @ W_up, stored bf16. 4 nodes/block.
__global__ __launch_bounds__(256) void node_up_kernel(const float* __restrict__ nf,
                                                      const float* __restrict__ W_up,
                                                      ushort* __restrict__ x_ws) {
    __shared__ float sW[64 * 64];
    __shared__ float sNf[4][64];
    int tid = threadIdx.x;
    size_t n0 = (size_t)blockIdx.x * 4;
    for (int i = tid; i < 4096; i += 256) sW[i] = W_up[i];
    {
        int r = tid >> 6, c = tid & 63;
        sNf[r][c] = nf[(n0 + r) * 64 + c];
    }
    __syncthreads();
    int r = tid >> 6, k = tid & 63;
    float acc = 0.f;
    #pragma unroll 8
    for (int c = 0; c < 64; ++c) acc += sNf[r][c] * sW[c * 64 + k];
    x_ws[(n0 + r) * 64 + k] = f2bf(acc);
}

// K2: histogram of receivers
__global__ __launch_bounds__(256) void hist_kernel(const int* __restrict__ recv,
                                                   int* __restrict__ counts, int E) {
    int e = blockIdx.x * 256 + threadIdx.x;
    if (e < E) atomicAdd(&counts[recv[e]], 1);
}

// K3: single-pass chunked exclusive scan counts -> offsets (and cursor copy)
__global__ __launch_bounds__(1024) void scan_kernel(const int* __restrict__ counts,
                                                    int* __restrict__ offsets,
                                                    int* __restrict__ cursor, int n) {
    __shared__ int wsums[16];
    int tid = threadIdx.x, lane = tid & 63, wid = tid >> 6;
    int CH = (n + 1023) >> 10;
    int base = tid * CH;
    int tot = 0;
    for (int j = 0; j < CH; ++j) {
        int i = base + j;
        if (i < n) tot += counts[i];
    }
    int v = tot;
    for (int off = 1; off < 64; off <<= 1) {
        int t = __shfl_up(v, off, 64);
        if (lane >= off) v += t;
    }
    if (lane == 63) wsums[wid] = v;
    __syncthreads();
    if (tid == 0) {
        int acc = 0;
        for (int w = 0; w < 16; ++w) { int t = wsums[w]; wsums[w] = acc; acc += t; }
    }
    __syncthreads();
    int excl = wsums[wid] + v - tot;
    for (int j = 0; j < CH; ++j) {
        int i = base + j;
        if (i < n) { offsets[i] = excl; cursor[i] = excl; excl += counts[i]; }
    }
    if (tid == 1023) offsets[n] = excl;
}

// K4: scatter into CSR order: sender, node, angular(float4 m=0..3), radial(bf16x8)
__global__ __launch_bounds__(256) void scatter_kernel(const int* __restrict__ recv,
                                                      const int* __restrict__ sender,
                                                      const float* __restrict__ angular,
                                                      const float* __restrict__ radial,
                                                      int* __restrict__ cursor,
                                                      int* __restrict__ csr_sender,
                                                      int* __restrict__ csr_node,
                                                      float4* __restrict__ csr_ang,
                                                      ushort* __restrict__ csr_radb, int E) {
    int e = blockIdx.x * 256 + threadIdx.x;
    if (e < E) {
        int r = recv[e];
        int pos = atomicAdd(&cursor[r], 1);
        csr_sender[pos] = sender[e];
        csr_node[pos] = r;
        csr_ang[pos] = *(const float4*)(angular + (size_t)e * 16);
        float4 r0 = *(const float4*)(radial + (size_t)e * 8);
        float4 r1 = *(const float4*)(radial + (size_t)e * 8 + 4);
        s16x8 rb;
        rb[0] = (short)f2bf(r0.x); rb[1] = (short)f2bf(r0.y);
        rb[2] = (short)f2bf(r0.z); rb[3] = (short)f2bf(r0.w);
        rb[4] = (short)f2bf(r1.x); rb[5] = (short)f2bf(r1.y);
        rb[6] = (short)f2bf(r1.z); rb[7] = (short)f2bf(r1.w);
        *(s16x8*)(csr_radb + (size_t)pos * 8) = rb;
    }
}

// K_prep: bake bf16 weight images.
// wimg ushort layout:
//   [0,4096)      W1t  (64m x 64k, k<8 real else 0), A-side swizzle
//   [4096,8192)   W2t  (64 x 64)
//   [8192,12288)  W3t  (64 x 64)
//   [12288,20480) W4t  (128m x 64k)
//   [20480,29696) wl_img: (l*64+col)*72 + c  = W_lin[l][c][col]
//   [29696,38912) wp_img: (l*64+col)*72 + c  = W_p{l}[c][col]
__global__ __launch_bounds__(256) void prep_kernel(const float* __restrict__ W1,
                                                   const float* __restrict__ W2,
                                                   const float* __restrict__ W3,
                                                   const float* __restrict__ W4,
                                                   const float* __restrict__ W_lin,
                                                   const float* __restrict__ Wp0,
                                                   const float* __restrict__ Wp1,
                                                   ushort* __restrict__ wimg) {
    int idx = blockIdx.x * 256 + threadIdx.x;
    if (idx < 4096) {
        int m = idx >> 6, k = idx & 63;
        int dst = m * 64 + ((((k >> 3) ^ (m & 7))) << 3) + (k & 7);
        wimg[dst] = (k < 8) ? f2bf(W1[k * 64 + m]) : (ushort)0;
    } else if (idx < 8192) {
        int i = idx - 4096;
        int m = i >> 6, k = i & 63;
        int dst = 4096 + m * 64 + ((((k >> 3) ^ (m & 7))) << 3) + (k & 7);
        wimg[dst] = f2bf(W2[k * 64 + m]);
    } else if (idx < 12288) {
        int i = idx - 8192;
        int m = i >> 6, k = i & 63;
        int dst = 8192 + m * 64 + ((((k >> 3) ^ (m & 7))) << 3) + (k & 7);
        wimg[dst] = f2bf(W3[k * 64 + m]);
    } else if (idx < 20480) {
        int i = idx - 12288;
        int m = i >> 6, k = i & 63;  // m in 0..127
        int dst = 12288 + m * 64 + ((((k >> 3) ^ (m & 7))) << 3) + (k & 7);
        wimg[dst] = f2bf(W4[k * 256 + m]);
    } else if (idx < 29696) {
        int i = idx - 20480;
        int row = i / 72, k = i % 72;
        int l = row >> 6, col = row & 63;
        wimg[idx] = (k < 64) ? f2bf(W_lin[l * 4096 + k * 64 + col]) : (ushort)0;
    } else if (idx < 38912) {
        int i = idx - 29696;
        int row = i / 72, k = i % 72;
        int l = row >> 6, col = row & 63;
        const float* Wp = l ? Wp1 : Wp0;
        wimg[idx] = (k < 64) ? f2bf(Wp[k * 64 + col]) : (ushort)0;
    }
}

// K5: fused edge MLP + CSR aggregation. Wave owns 64 contiguous CSR positions,
// 4 subpasses of 16 edges (MLP via MFMA into bounce LDS, then accumulate).
__global__ __launch_bounds__(256) void edge_fused_kernel(
    const ushort* __restrict__ csr_radb, const ushort* __restrict__ wimg,
    const int* __restrict__ csr_sender, const int* __restrict__ csr_node,
    const float4* __restrict__ csr_ang, const ushort* __restrict__ x_ws,
    float* __restrict__ agg_f, int E) {
    __shared__ __align__(16) ushort sW4[8192];
    __shared__ __align__(16) ushort sB[4][2048];  // per-wave bounce, 4KB each
    int tid = threadIdx.x, lane = tid & 63, wave = tid >> 6;
    int n = lane & 15, hi = lane >> 4;

    for (int i = tid; i < 1024; i += 256)
        ((s16x8*)sW4)[i] = ((const s16x8*)(wimg + 12288))[i];

    // preload A-side weight fragments (VGPR-resident, block-invariant)
    s16x8 w1f[4], w2f[4][2], w3f[4][2];
    #pragma unroll
    for (int mt = 0; mt < 4; ++mt) {
        int row = mt * 16 + n, r7 = row & 7;
        w1f[mt] = *(const s16x8*)(wimg + row * 64 + ((hi ^ r7) << 3));
        #pragma unroll
        for (int ks = 0; ks < 2; ++ks) {
            w2f[mt][ks] = *(const s16x8*)(wimg + 4096 + row * 64 + (((ks * 4 + hi) ^ r7) << 3));
            w3f[mt][ks] = *(const s16x8*)(wimg + 8192 + row * 64 + (((ks * 4 + hi) ^ r7) << 3));
        }
    }
    __syncthreads();

    char* myB = (char*)sB[wave];
    int n7 = n & 7;

    int lo = blockIdx.x * 256 + wave * 64;
    if (lo >= E) return;
    int hi_pos = min(lo + 64, E);
    int nfirst = csr_node[lo];
    int nlast = csr_node[hi_pos - 1];
    int cur_node = nfirst;
    float a0 = 0, a1 = 0, a2 = 0, a3 = 0;

    auto flush = [&](int nodeid) {
        size_t b = (size_t)nodeid * 256 + lane;
        if (nodeid == nfirst || nodeid == nlast) {
            atomicAdd(&agg_f[b], a0 * 0.1f);
            atomicAdd(&agg_f[b + 64], a1 * 0.1f);
            atomicAdd(&agg_f[b + 128], a2 * 0.1f);
            atomicAdd(&agg_f[b + 192], a3 * 0.1f);
        } else {
            agg_f[b] = a0 * 0.1f;
            agg_f[b + 64] = a1 * 0.1f;
            agg_f[b + 128] = a2 * 0.1f;
            agg_f[b + 192] = a3 * 0.1f;
        }
    };

    for (int sub = 0; sub < 4; ++sub) {
        int base = lo + sub * 16;
        if (base >= E) break;
        int pos16 = min(base + n, E - 1);
        // per-lane preloads (lane i holds position base+i for i<16... replicated)
        int pl = min(base + (lane & 15), E - 1);
        int sv = csr_sender[pl];
        int nv = csr_node[pl];

        // radial B-fragment
        s16x8 bR;
        #pragma unroll
        for (int j = 0; j < 8; ++j) bR[j] = 0;
        if (hi == 0) bR = *(const s16x8*)(csr_radb + (size_t)pos16 * 8);

        f32x4 zero = {0.f, 0.f, 0.f, 0.f};
        f32x4 d[4];
        // L1 (K=32, zero-padded)
        #pragma unroll
        for (int mt = 0; mt < 4; ++mt)
            d[mt] = __builtin_amdgcn_mfma_f32_16x16x32_bf16(w1f[mt], bR, zero, 0, 0, 0);

        #pragma unroll
        for (int mt = 0; mt < 4; ++mt) {
            unsigned p0 = pack2(silu_f(d[mt][0]), silu_f(d[mt][1]));
            unsigned p1 = pack2(silu_f(d[mt][2]), silu_f(d[mt][3]));
            int slot = mt * 2 + (hi >> 1);
            uint2 val = {p0, p1};
            *(uint2*)(myB + n * 128 + ((slot ^ n7) << 4) + (hi & 1) * 8) = val;
        }
        s16x8 b0 = *(const s16x8*)(myB + n * 128 + ((hi ^ n7) << 4));
        s16x8 b1 = *(const s16x8*)(myB + n * 128 + (((4 + hi) ^ n7) << 4));

        // L2
        #pragma unroll
        for (int mt = 0; mt < 4; ++mt) {
            d[mt] = __builtin_amdgcn_mfma_f32_16x16x32_bf16(w2f[mt][0], b0, zero, 0, 0, 0);
            d[mt] = __builtin_amdgcn_mfma_f32_16x16x32_bf16(w2f[mt][1], b1, d[mt], 0, 0, 0);
        }
        #pragma unroll
        for (int mt = 0; mt < 4; ++mt) {
            unsigned p0 = pack2(silu_f(d[mt][0]), silu_f(d[mt][1]));
            unsigned p1 = pack2(silu_f(d[mt][2]), silu_f(d[mt][3]));
            int slot = mt * 2 + (hi >> 1);
            uint2 val = {p0, p1};
            *(uint2*)(myB + n * 128 + ((slot ^ n7) << 4) + (hi & 1) * 8) = val;
        }
        b0 = *(const s16x8*)(myB + n * 128 + ((hi ^ n7) << 4));
        b1 = *(const s16x8*)(myB + n * 128 + (((4 + hi) ^ n7) << 4));

        // L3
        #pragma unroll
        for (int mt = 0; mt < 4; ++mt) {
            d[mt] = __builtin_amdgcn_mfma_f32_16x16x32_bf16(w3f[mt][0], b0, zero, 0, 0, 0);
            d[mt] = __builtin_amdgcn_mfma_f32_16x16x32_bf16(w3f[mt][1], b1, d[mt], 0, 0, 0);
        }
        #pragma unroll
        for (int mt = 0; mt < 4; ++mt) {
            unsigned p0 = pack2(silu_f(d[mt][0]), silu_f(d[mt][1]));
            unsigned p1 = pack2(silu_f(d[mt][2]), silu_f(d[mt][3]));
            int slot = mt * 2 + (hi >> 1);
            uint2 val = {p0, p1};
            *(uint2*)(myB + n * 128 + ((slot ^ n7) << 4) + (hi & 1) * 8) = val;
        }
        b0 = *(const s16x8*)(myB + n * 128 + ((hi ^ n7) << 4));
        b1 = *(const s16x8*)(myB + n * 128 + (((4 + hi) ^ n7) << 4));

        // L4: 128 outputs (l=0,1), A from LDS sW4
        f32x4 o[8];
        #pragma unroll
        for (int mt = 0; mt < 8; ++mt) {
            int row = mt * 16 + n, r7 = row & 7;
            s16x8 a0f = *(const s16x8*)(sW4 + row * 64 + ((hi ^ r7) << 3));
            s16x8 a1f = *(const s16x8*)(sW4 + row * 64 + (((4 + hi) ^ r7) << 3));
            o[mt] = __builtin_amdgcn_mfma_f32_16x16x32_bf16(a0f, b0, zero, 0, 0, 0);
            o[mt] = __builtin_amdgcn_mfma_f32_16x16x32_bf16(a1f, b1, o[mt], 0, 0, 0);
        }
        // pack tp rows into bounce: row=edge (256B), slot = chslot ^ edge
        #pragma unroll
        for (int mt = 0; mt < 8; ++mt) {
            unsigned p0 = pack2(o[mt][0], o[mt][1]);
            unsigned p1 = pack2(o[mt][2], o[mt][3]);
            int slot = mt * 2 + (hi >> 1);
            uint2 val = {p0, p1};
            *(uint2*)(myB + n * 256 + ((slot ^ n) << 4) + (hi & 1) * 8) = val;
        }

        // ---- aggregation over this subpass's edges ----
        int cnt = min(16, E - base);
        ushort xa = x_ws[(size_t)__shfl(sv, 0) * 64 + lane];
        ushort xb = 0;
        if (cnt > 1) xb = x_ws[(size_t)__shfl(sv, 1) * 64 + lane];
        for (int e = 0; e < cnt; ++e) {
            ushort xc = 0;
            if (e + 2 < cnt) xc = x_ws[(size_t)__shfl(sv, e + 2) * 64 + lane];
            int node = __shfl(nv, e);
            if (node != cur_node) {
                flush(cur_node);
                a0 = a1 = a2 = a3 = 0;
                cur_node = node;
            }
            float4 ang = csr_ang[base + e];
            float x = bf2f(xa);
            float tp0 = bf2f(*(const ushort*)(myB + e * 256 +
                             (((lane >> 3) ^ e) << 4) + (lane & 7) * 2));
            float tp1 = bf2f(*(const ushort*)(myB + e * 256 +
                             ((((lane >> 3) | 8) ^ e) << 4) + (lane & 7) * 2));
            float y0 = x * tp0, y1 = x * tp1;
            a0 += ang.x * y0;
            a1 += ang.y * y1;
            a2 += ang.z * y1;
            a3 += ang.w * y1;
            xa = xb; xb = xc;
        }
    }
    flush(cur_node);
}

// K6: per-32-node tile: feats = agg@W_lin (MFMA), scale by wn, out = f@W_p (+sc0).
__global__ __launch_bounds__(256) void node_out2_kernel(
    const float* __restrict__ nf, const float* __restrict__ one_hot,
    const ushort* __restrict__ wimg, const float* __restrict__ W_skip,
    const float* __restrict__ W_c0, const float* __restrict__ W_c1,
    const float* __restrict__ agg_f, float* __restrict__ out) {
    __shared__ __align__(16) ushort sWl[2 * 64 * 72];
    __shared__ __align__(16) ushort sF[4][32 * 72];
    __shared__ float sSc[32][64];
    __shared__ float sWc[2][640];
    __shared__ int sElem[32];
    int tid = threadIdx.x;
    int n0 = blockIdx.x * 32;
    int lane = tid & 63, m = tid >> 6;
    int lsel = (m == 0) ? 0 : 1;

    // direct-from-global W_p B-fragments (L2-resident image)
    s16x8 pf[4][2];
    #pragma unroll
    for (int nt = 0; nt < 4; ++nt)
        #pragma unroll
        for (int ks = 0; ks < 2; ++ks)
            pf[nt][ks] = *(const s16x8*)(wimg + 29696 +
                (lsel * 64 + nt * 16 + (lane & 15)) * 72 + ks * 32 + (lane >> 4) * 8);

    for (int i = tid; i < 1152; i += 256)
        ((s16x8*)sWl)[i] = ((const s16x8*)(wimg + 20480))[i];
    for (int i = tid; i < 1280; i += 256)
        sWc[i >= 640][i % 640] = (i >= 640 ? W_c1 : W_c0)[i % 640];
    if (tid < 32) {
        int nn = n0 + tid, e = 0;
        for (int a = 0; a < 10; ++a)
            if (one_hot[(size_t)nn * 10 + a] > 0.5f) { e = a; break; }
        sElem[tid] = e;
    }
    __syncthreads();

    // sc0 skip connection: 8 threads per node, 8 k's per thread
    {
        int nl = tid >> 3, k0 = (tid & 7) * 8;
        int nn = n0 + nl, elem = sElem[nl];
        float acc[8] = {0, 0, 0, 0, 0, 0, 0, 0};
        for (int c = 0; c < 64; ++c) {
            float v = nf[(size_t)nn * 64 + c];
            const float* wr = W_skip + ((size_t)c * 10 + elem) * 64 + k0;
            #pragma unroll
            for (int j = 0; j < 8; ++j) acc[j] += v * wr[j];
        }
        #pragma unroll
        for (int j = 0; j < 8; ++j) sSc[nl][k0 + j] = acc[j];
    }

    // GEMM1: feats[m] = agg[:,m,:] @ W_lin[lsel]   (M=32, K=64, N=64)
    f32x4 acc[2][4] = {};
    s16x8 afr[2][2];
    #pragma unroll
    for (int mt = 0; mt < 2; ++mt)
        #pragma unroll
        for (int ks = 0; ks < 2; ++ks) {
            const float* src = agg_f + ((size_t)(n0 + mt * 16 + (lane & 15))) * 256 +
                               m * 64 + ks * 32 + (lane >> 4) * 8;
            float4 u0 = *(const float4*)src;
            float4 u1 = *(const float4*)(src + 4);
            s16x8 f;
            f[0] = (short)f2bf(u0.x); f[1] = (short)f2bf(u0.y);
            f[2] = (short)f2bf(u0.z); f[3] = (short)f2bf(u0.w);
            f[4] = (short)f2bf(u1.x); f[5] = (short)f2bf(u1.y);
            f[6] = (short)f2bf(u1.z); f[7] = (short)f2bf(u1.w);
            afr[mt][ks] = f;
        }
    #pragma unroll
    for (int nt = 0; nt < 4; ++nt)
        #pragma unroll
        for (int ks = 0; ks < 2; ++ks) {
            s16x8 b = *(const s16x8*)(sWl + (lsel * 64 + nt * 16 + (lane & 15)) * 72 +
                                      ks * 32 + (lane >> 4) * 8);
            #pragma unroll
            for (int mt = 0; mt < 2; ++mt)
                acc[mt][nt] = __builtin_amdgcn_mfma_f32_16x16x32_bf16(afr[mt][ks], b,
                                                                      acc[mt][nt], 0, 0, 0);
        }

    // scale by wn and write bf16 to sF
    #pragma unroll
    for (int mt = 0; mt < 2; ++mt)
        #pragma unroll
        for (int nt = 0; nt < 4; ++nt)
            #pragma unroll
            for (int r = 0; r < 4; ++r) {
                int nl = mt * 16 + (lane >> 4) * 4 + r;
                int k = nt * 16 + (lane & 15);
                float scale = sWc[lsel][sElem[nl] * 64 + k];
                sF[m][nl * 72 + k] = f2bf(acc[mt][nt][r] * scale);
            }
    __syncthreads();

    // GEMM2: out_m = f[m] @ W_p{0|1}
    f32x4 acc2[2][4] = {};
    s16x8 af2[2][2];
    #pragma unroll
    for (int mt = 0; mt < 2; ++mt)
        #pragma unroll
        for (int ks = 0; ks < 2; ++ks)
            af2[mt][ks] = *(const s16x8*)(&sF[m][(mt * 16 + (lane & 15)) * 72 +
                                                 ks * 32 + (lane >> 4) * 8]);
    #pragma unroll
    for (int nt = 0; nt < 4; ++nt)
        #pragma unroll
        for (int ks = 0; ks < 2; ++ks) {
            #pragma unroll
            for (int mt = 0; mt < 2; ++mt)
                acc2[mt][nt] = __builtin_amdgcn_mfma_f32_16x16x32_bf16(af2[mt][ks],
                                                                       pf[nt][ks],
                                                                       acc2[mt][nt], 0, 0, 0);
        }

    // epilogue
    #pragma unroll
    for (int mt = 0; mt < 2; ++mt)
        #pragma unroll
        for (int nt = 0; nt < 4; ++nt)
            #pragma unroll
            for (int r = 0; r < 4; ++r) {
                int nl = mt * 16 + (lane >> 4) * 4 + r;
                int k = nt * 16 + (lane & 15);
                size_t nn = (size_t)n0 + nl;
                if (m == 0)
                    out[nn * 256 + k] = acc2[mt][nt][r] + sSc[nl][k];
                else
                    out[nn * 256 + 64 + k * 3 + (m - 1)] = acc2[mt][nt][r];
            }
}

extern "C" void kernel_launch(void* const* d_in, const int* in_sizes, int n_in,
                              void* d_out, int out_size, void* d_ws, size_t ws_size,
                              hipStream_t stream) {
    const float* node_features = (const float*)d_in[0];
    const float* one_hot = (const float*)d_in[1];
    const float* angular = (const float*)d_in[2];
    const float* radial = (const float*)d_in[3];
    const float* W_up = (const float*)d_in[4];
    const float* W_mlp1 = (const float*)d_in[5];
    const float* W_mlp2 = (const float*)d_in[6];
    const float* W_mlp3 = (const float*)d_in[7];
    const float* W_mlp4 = (const float*)d_in[8];
    const float* W_lin = (const float*)d_in[9];
    const float* W_skip = (const float*)d_in[10];
    const float* W_c0 = (const float*)d_in[11];
    const float* W_c1 = (const float*)d_in[12];
    const float* W_p0 = (const float*)d_in[13];
    const float* W_p1 = (const float*)d_in[14];
    const int* edge_index = (const int*)d_in[15];
    float* out = (float*)d_out;

    int N = in_sizes[0] / 64;
    int E = in_sizes[2] / 16;
    const int* sender = edge_index;
    const int* receiver = edge_index + E;

    char* p = (char*)d_ws;
    ushort* x_ws = (ushort*)p;      p += (size_t)N * 64 * 2;
    float* agg_f = (float*)p;       p += (size_t)N * 256 * 4;
    ushort* wimg = (ushort*)p;      p += 38912 * 2;
    float4* csr_ang = (float4*)p;   p += (size_t)E * 16;
    ushort* csr_radb = (ushort*)p;  p += (size_t)E * 8 * 2;
    int* counts = (int*)p;          p += (size_t)N * 4;
    int* offsets = (int*)p;         p += (size_t)(N + 1) * 4;
    int* cursor = (int*)p;          p += (size_t)N * 4;
    int* csr_sender = (int*)p;      p += (size_t)E * 4;
    int* csr_node = (int*)p;        p += (size_t)E * 4;

    hipMemsetAsync(counts, 0, (size_t)N * 4, stream);
    hipMemsetAsync(agg_f, 0, (size_t)N * 256 * 4, stream);
    prep_kernel<<<152, 256, 0, stream>>>(W_mlp1, W_mlp2, W_mlp3, W_mlp4,
                                         W_lin, W_p0, W_p1, wimg);
    node_up_kernel<<<N / 4, 256, 0, stream>>>(node_features, W_up, x_ws);
    hist_kernel<<<(E + 255) / 256, 256, 0, stream>>>(receiver, counts, E);
    scan_kernel<<<1, 1024, 0, stream>>>(counts, offsets, cursor, N);
    scatter_kernel<<<(E + 255) / 256, 256, 0, stream>>>(receiver, sender, angular,
                                                        radial, cursor, csr_sender,
                                                        csr_node, csr_ang, csr_radb, E);
    edge_fused_kernel<<<(E + 255) / 256, 256, 0, stream>>>(csr_radb, wimg, csr_sender,
                                                           csr_node, csr_ang, x_ws,
                                                           agg_f, E);
    node_out2_kernel<<<N / 32, 256, 0, stream>>>(node_features, one_hot, wimg, W_skip,
                                                 W_c0, W_c1, agg_f, out);
}

// Round 5
// 172.775 us; speedup vs baseline: 1.2042x; 1.2042x over previous
//
#include <hip/hip_runtime.h>

typedef __attribute__((ext_vector_type(8))) short s16x8;
typedef __attribute__((ext_vector_type(4))) float f32x4;

__device__ inline float bf2f(ushort u) {
    union { unsigned int i; float f; } v; v.i = ((unsigned)u) << 16; return v.f;
}
__device__ inline ushort f2bf(float f) {
    union { float f; unsigned int i; } v; v.f = f;
    unsigned r = v.i + 0x7FFFu + ((v.i >> 16) & 1u);
    return (ushort)(r >> 16);
}
__device__ inline unsigned cvt_pk(float lo, float hi) {
    unsigned d;
    asm("v_cvt_pk_bf16_f32 %0, %1, %2" : "=v"(d) : "v"(lo), "v"(hi));
    return d;
}
__device__ inline float silu_f(float x) { return x / (1.f + __expf(-x)); }

// K1: x = node_features @ W_up, stored bf16. 4 nodes/block.
__global__ __launch_bounds__(256) void node_up_kernel(const float* __restrict__ nf,
                                                      const float* __restrict__ W_up,
                                                      ushort* __restrict__ x_ws) {
    __shared__ float sW[64 * 64];
    __shared__ float sNf[4][64];
    int tid = threadIdx.x;
    size_t n0 = (size_t)blockIdx.x * 4;
    for (int i = tid; i < 4096; i += 256) sW[i] = W_up[i];
    {
        int r = tid >> 6, c = tid & 63;
        sNf[r][c] = nf[(n0 + r) * 64 + c];
    }
    __syncthreads();
    int r = tid >> 6, k = tid & 63;
    float acc = 0.f;
    #pragma unroll 8
    for (int c = 0; c < 64; ++c) acc += sNf[r][c] * sW[c * 64 + k];
    x_ws[(n0 + r) * 64 + k] = f2bf(acc);
}

// K2: histogram of receivers
__global__ __launch_bounds__(256) void hist_kernel(const int* __restrict__ recv,
                                                   int* __restrict__ counts, int E) {
    int e = blockIdx.x * 256 + threadIdx.x;
    if (e < E) atomicAdd(&counts[recv[e]], 1);
}

// K3: single-pass chunked exclusive scan counts -> offsets (and cursor copy)
__global__ __launch_bounds__(1024) void scan_kernel(const int* __restrict__ counts,
                                                    int* __restrict__ offsets,
                                                    int* __restrict__ cursor, int n) {
    __shared__ int wsums[16];
    int tid = threadIdx.x, lane = tid & 63, wid = tid >> 6;
    int CH = (n + 1023) >> 10;
    int base = tid * CH;
    int tot = 0;
    for (int j = 0; j < CH; ++j) {
        int i = base + j;
        if (i < n) tot += counts[i];
    }
    int v = tot;
    for (int off = 1; off < 64; off <<= 1) {
        int t = __shfl_up(v, off, 64);
        if (lane >= off) v += t;
    }
    if (lane == 63) wsums[wid] = v;
    __syncthreads();
    if (tid == 0) {
        int acc = 0;
        for (int w = 0; w < 16; ++w) { int t = wsums[w]; wsums[w] = acc; acc += t; }
    }
    __syncthreads();
    int excl = wsums[wid] + v - tot;
    for (int j = 0; j < CH; ++j) {
        int i = base + j;
        if (i < n) { offsets[i] = excl; cursor[i] = excl; excl += counts[i]; }
    }
    if (tid == 1023) offsets[n] = excl;
}

// K4: scatter into CSR order: sender, angular(float4 m=0..3), radial(bf16x8)
__global__ __launch_bounds__(256) void scatter_kernel(const int* __restrict__ recv,
                                                      const int* __restrict__ sender,
                                                      const float* __restrict__ angular,
                                                      const float* __restrict__ radial,
                                                      int* __restrict__ cursor,
                                                      int* __restrict__ csr_sender,
                                                      float4* __restrict__ csr_ang,
                                                      ushort* __restrict__ csr_radb, int E) {
    int e = blockIdx.x * 256 + threadIdx.x;
    if (e < E) {
        int r = recv[e];
        int pos = atomicAdd(&cursor[r], 1);
        csr_sender[pos] = sender[e];
        csr_ang[pos] = *(const float4*)(angular + (size_t)e * 16);
        float4 r0 = *(const float4*)(radial + (size_t)e * 8);
        float4 r1 = *(const float4*)(radial + (size_t)e * 8 + 4);
        uint2 lo = {cvt_pk(r0.x, r0.y), cvt_pk(r0.z, r0.w)};
        uint2 hi = {cvt_pk(r1.x, r1.y), cvt_pk(r1.z, r1.w)};
        *(uint2*)(csr_radb + (size_t)pos * 8) = lo;
        *(uint2*)(csr_radb + (size_t)pos * 8 + 4) = hi;
    }
}

// K_prep: bake bf16 weight images.
// wimg ushort layout:
//   [0,4096)       W1t  (64m x 64k, k<8 real else 0), A-side swizzle
//   [4096,8192)    W2t  (64 x 64)
//   [8192,12288)   W3t  (64 x 64)
//   [12288,20480)  W4t  (128m x 64k)
//   [20480,29696)  wl_img: (l*64+col)*72 + c  = W_lin[l][c][col]
//   [29696,38912)  wp_img: (l*64+col)*72 + c  = W_p{l}[c][col]
//   [38912,79872)  wskb: W_skip bf16 linear (c*10+a)*64+k
__global__ __launch_bounds__(256) void prep_kernel(const float* __restrict__ W1,
                                                   const float* __restrict__ W2,
                                                   const float* __restrict__ W3,
                                                   const float* __restrict__ W4,
                                                   const float* __restrict__ W_lin,
                                                   const float* __restrict__ Wp0,
                                                   const float* __restrict__ Wp1,
                                                   const float* __restrict__ W_skip,
                                                   ushort* __restrict__ wimg) {
    int idx = blockIdx.x * 256 + threadIdx.x;
    if (idx < 4096) {
        int m = idx >> 6, k = idx & 63;
        int dst = m * 64 + ((((k >> 3) ^ (m & 7))) << 3) + (k & 7);
        wimg[dst] = (k < 8) ? f2bf(W1[k * 64 + m]) : (ushort)0;
    } else if (idx < 8192) {
        int i = idx - 4096;
        int m = i >> 6, k = i & 63;
        int dst = 4096 + m * 64 + ((((k >> 3) ^ (m & 7))) << 3) + (k & 7);
        wimg[dst] = f2bf(W2[k * 64 + m]);
    } else if (idx < 12288) {
        int i = idx - 8192;
        int m = i >> 6, k = i & 63;
        int dst = 8192 + m * 64 + ((((k >> 3) ^ (m & 7))) << 3) + (k & 7);
        wimg[dst] = f2bf(W3[k * 64 + m]);
    } else if (idx < 20480) {
        int i = idx - 12288;
        int m = i >> 6, k = i & 63;  // m in 0..127
        int dst = 12288 + m * 64 + ((((k >> 3) ^ (m & 7))) << 3) + (k & 7);
        wimg[dst] = f2bf(W4[k * 256 + m]);
    } else if (idx < 29696) {
        int i = idx - 20480;
        int row = i / 72, k = i % 72;
        int l = row >> 6, col = row & 63;
        wimg[idx] = (k < 64) ? f2bf(W_lin[l * 4096 + k * 64 + col]) : (ushort)0;
    } else if (idx < 38912) {
        int i = idx - 29696;
        int row = i / 72, k = i % 72;
        int l = row >> 6, col = row & 63;
        const float* Wp = l ? Wp1 : Wp0;
        wimg[idx] = (k < 64) ? f2bf(Wp[k * 64 + col]) : (ushort)0;
    } else if (idx < 79872) {
        int i = idx - 38912;
        wimg[idx] = f2bf(W_skip[i]);
    }
}

// K5: edge MLP, operand-swapped (D = W^T h^T). 128 edges/block, wave owns 32
// edges (2 subpasses of 16). L4 result stored directly from D-fragments.
__global__ __launch_bounds__(256) void edge_mlp_kernel(const ushort* __restrict__ csr_radb,
                                                       const ushort* __restrict__ wimg,
                                                       ushort* __restrict__ tpw, int E) {
    __shared__ __align__(16) ushort sW4[8192];       // 16KB
    __shared__ __align__(16) ushort sB[4][1024];     // per-wave h bounce, 2KB each
    int tid = threadIdx.x, lane = tid & 63, wave = tid >> 6;
    int n = lane & 15, hi = lane >> 4;

    for (int i = tid; i < 1024; i += 256)
        ((s16x8*)sW4)[i] = ((const s16x8*)(wimg + 12288))[i];

    // preload A-side weight fragments (VGPR-resident, block-invariant)
    s16x8 w1f[4], w2f[4][2], w3f[4][2];
    #pragma unroll
    for (int mt = 0; mt < 4; ++mt) {
        int row = mt * 16 + n, r7 = row & 7;
        w1f[mt] = *(const s16x8*)(wimg + row * 64 + ((hi ^ r7) << 3));
        #pragma unroll
        for (int ks = 0; ks < 2; ++ks) {
            w2f[mt][ks] = *(const s16x8*)(wimg + 4096 + row * 64 + (((ks * 4 + hi) ^ r7) << 3));
            w3f[mt][ks] = *(const s16x8*)(wimg + 8192 + row * 64 + (((ks * 4 + hi) ^ r7) << 3));
        }
    }
    __syncthreads();

    char* myB = (char*)sB[wave];
    int n7 = n & 7;

    for (int sub = 0; sub < 2; ++sub) {
        int base = blockIdx.x * 128 + wave * 32 + sub * 16;
        if (base >= E) break;
        int pos16 = min(base + n, E - 1);

        // radial B-fragment (k = hi*8+j; only k<8 real)
        s16x8 bR;
        #pragma unroll
        for (int j = 0; j < 8; ++j) bR[j] = 0;
        if (hi == 0) bR = *(const s16x8*)(csr_radb + (size_t)pos16 * 8);

        f32x4 zero = {0.f, 0.f, 0.f, 0.f};
        f32x4 d[4];
        // L1 (K=32, zero-padded)
        #pragma unroll
        for (int mt = 0; mt < 4; ++mt)
            d[mt] = __builtin_amdgcn_mfma_f32_16x16x32_bf16(w1f[mt], bR, zero, 0, 0, 0);

        #pragma unroll
        for (int mt = 0; mt < 4; ++mt) {
            uint2 val = {cvt_pk(silu_f(d[mt][0]), silu_f(d[mt][1])),
                         cvt_pk(silu_f(d[mt][2]), silu_f(d[mt][3]))};
            int slot = mt * 2 + (hi >> 1);
            *(uint2*)(myB + n * 128 + ((slot ^ n7) << 4) + (hi & 1) * 8) = val;
        }
        s16x8 b0 = *(const s16x8*)(myB + n * 128 + ((hi ^ n7) << 4));
        s16x8 b1 = *(const s16x8*)(myB + n * 128 + (((4 + hi) ^ n7) << 4));

        // L2
        #pragma unroll
        for (int mt = 0; mt < 4; ++mt) {
            d[mt] = __builtin_amdgcn_mfma_f32_16x16x32_bf16(w2f[mt][0], b0, zero, 0, 0, 0);
            d[mt] = __builtin_amdgcn_mfma_f32_16x16x32_bf16(w2f[mt][1], b1, d[mt], 0, 0, 0);
        }
        #pragma unroll
        for (int mt = 0; mt < 4; ++mt) {
            uint2 val = {cvt_pk(silu_f(d[mt][0]), silu_f(d[mt][1])),
                         cvt_pk(silu_f(d[mt][2]), silu_f(d[mt][3]))};
            int slot = mt * 2 + (hi >> 1);
            *(uint2*)(myB + n * 128 + ((slot ^ n7) << 4) + (hi & 1) * 8) = val;
        }
        b0 = *(const s16x8*)(myB + n * 128 + ((hi ^ n7) << 4));
        b1 = *(const s16x8*)(myB + n * 128 + (((4 + hi) ^ n7) << 4));

        // L3
        #pragma unroll
        for (int mt = 0; mt < 4; ++mt) {
            d[mt] = __builtin_amdgcn_mfma_f32_16x16x32_bf16(w3f[mt][0], b0, zero, 0, 0, 0);
            d[mt] = __builtin_amdgcn_mfma_f32_16x16x32_bf16(w3f[mt][1], b1, d[mt], 0, 0, 0);
        }
        #pragma unroll
        for (int mt = 0; mt < 4; ++mt) {
            uint2 val = {cvt_pk(silu_f(d[mt][0]), silu_f(d[mt][1])),
                         cvt_pk(silu_f(d[mt][2]), silu_f(d[mt][3]))};
            int slot = mt * 2 + (hi >> 1);
            *(uint2*)(myB + n * 128 + ((slot ^ n7) << 4) + (hi & 1) * 8) = val;
        }
        b0 = *(const s16x8*)(myB + n * 128 + ((hi ^ n7) << 4));
        b1 = *(const s16x8*)(myB + n * 128 + (((4 + hi) ^ n7) << 4));

        // L4: 128 outputs (l=0,1), A from LDS sW4; store D-fragments directly.
        bool ok = (base + n) < E;
        size_t rowbase = (size_t)(base + n) * 128;
        #pragma unroll
        for (int mt = 0; mt < 8; ++mt) {
            int row = mt * 16 + n, r7 = row & 7;
            s16x8 a0f = *(const s16x8*)(sW4 + row * 64 + ((hi ^ r7) << 3));
            s16x8 a1f = *(const s16x8*)(sW4 + row * 64 + (((4 + hi) ^ r7) << 3));
            f32x4 o = __builtin_amdgcn_mfma_f32_16x16x32_bf16(a0f, b0, zero, 0, 0, 0);
            o = __builtin_amdgcn_mfma_f32_16x16x32_bf16(a1f, b1, o, 0, 0, 0);
            if (ok) {
                uint2 val = {cvt_pk(o[0], o[1]), cvt_pk(o[2], o[3])};
                *(uint2*)(tpw + rowbase + mt * 16 + hi * 4) = val;
            }
        }
    }
}

// K6a: CSR aggregation. Wave per node, lane = channel, 2-deep x prefetch.
__global__ __launch_bounds__(256) void agg_kernel(const float4* __restrict__ csr_ang,
                                                  const int* __restrict__ csr_sender,
                                                  const ushort* __restrict__ tpw,
                                                  const int* __restrict__ offsets,
                                                  const ushort* __restrict__ x_ws,
                                                  ushort* __restrict__ agg, int N) {
    int wave = threadIdx.x >> 6, lane = threadIdx.x & 63;
    int node = blockIdx.x * 4 + wave;
    if (node >= N) return;
    int beg = offsets[node], end = offsets[node + 1];
    float a0 = 0, a1 = 0, a2 = 0, a3 = 0;
    ushort xa = 0, xb = 0;
    if (beg < end) xa = x_ws[(size_t)csr_sender[beg] * 64 + lane];
    if (beg + 1 < end) xb = x_ws[(size_t)csr_sender[beg + 1] * 64 + lane];
    for (int i = beg; i < end; ++i) {
        ushort xc = 0;
        if (i + 2 < end) xc = x_ws[(size_t)csr_sender[i + 2] * 64 + lane];
        float4 ang = csr_ang[i];
        float tp0 = bf2f(tpw[(size_t)i * 128 + lane]);
        float tp1 = bf2f(tpw[(size_t)i * 128 + 64 + lane]);
        float x = bf2f(xa);
        float y0 = x * tp0, y1 = x * tp1;
        a0 += ang.x * y0;
        a1 += ang.y * y1;
        a2 += ang.z * y1;
        a3 += ang.w * y1;
        xa = xb; xb = xc;
    }
    size_t b = (size_t)node * 256 + lane;
    agg[b] = f2bf(a0 * 0.1f);
    agg[b + 64] = f2bf(a1 * 0.1f);
    agg[b + 128] = f2bf(a2 * 0.1f);
    agg[b + 192] = f2bf(a3 * 0.1f);
}

// K6b: per-32-node tile: feats = agg@W_lin (MFMA), scale by wn, out = f@W_p (+sc0).
__global__ __launch_bounds__(256) void node_out2_kernel(
    const float* __restrict__ nf, const float* __restrict__ one_hot,
    const ushort* __restrict__ wimg, const float* __restrict__ W_c0,
    const float* __restrict__ W_c1, const ushort* __restrict__ agg,
    float* __restrict__ out) {
    __shared__ __align__(16) ushort sWl[2 * 64 * 72];
    __shared__ __align__(16) ushort sF[4][32 * 72];
    __shared__ float sSc[32][64];
    __shared__ float sWc[2][640];
    __shared__ int sElem[32];
    int tid = threadIdx.x;
    int n0 = blockIdx.x * 32;
    int lane = tid & 63, m = tid >> 6;
    int lsel = (m == 0) ? 0 : 1;

    // direct-from-global W_p B-fragments (L2-resident image)
    s16x8 pf[4][2];
    #pragma unroll
    for (int nt = 0; nt < 4; ++nt)
        #pragma unroll
        for (int ks = 0; ks < 2; ++ks)
            pf[nt][ks] = *(const s16x8*)(wimg + 29696 +
                (lsel * 64 + nt * 16 + (lane & 15)) * 72 + ks * 32 + (lane >> 4) * 8);

    for (int i = tid; i < 1152; i += 256)
        ((s16x8*)sWl)[i] = ((const s16x8*)(wimg + 20480))[i];
    for (int i = tid; i < 1280; i += 256)
        sWc[i >= 640][i % 640] = (i >= 640 ? W_c1 : W_c0)[i % 640];
    if (tid < 32) {
        int nn = n0 + tid, e = 0;
        for (int a = 0; a < 10; ++a)
            if (one_hot[(size_t)nn * 10 + a] > 0.5f) { e = a; break; }
        sElem[tid] = e;
    }
    __syncthreads();

    // sc0 skip connection: 8 threads per node, 8 k's per thread, bf16 W_skip
    {
        int nl = tid >> 3, k0 = (tid & 7) * 8;
        int nn = n0 + nl, elem = sElem[nl];
        float acc[8] = {0, 0, 0, 0, 0, 0, 0, 0};
        const ushort* wskb = wimg + 38912;
        for (int c = 0; c < 64; ++c) {
            float v = nf[(size_t)nn * 64 + c];
            s16x8 w = *(const s16x8*)(wskb + ((size_t)c * 10 + elem) * 64 + k0);
            #pragma unroll
            for (int j = 0; j < 8; ++j) acc[j] += v * bf2f((ushort)w[j]);
        }
        #pragma unroll
        for (int j = 0; j < 8; ++j) sSc[nl][k0 + j] = acc[j];
    }

    // GEMM1: feats[m] = agg[:,m,:] @ W_lin[lsel]   (M=32, K=64, N=64)
    f32x4 acc[2][4] = {};
    s16x8 afr[2][2];
    #pragma unroll
    for (int mt = 0; mt < 2; ++mt)
        #pragma unroll
        for (int ks = 0; ks < 2; ++ks)
            afr[mt][ks] = *(const s16x8*)(agg +
                (((size_t)(n0 + mt * 16 + (lane & 15))) * 4 + m) * 64 +
                ks * 32 + (lane >> 4) * 8);
    #pragma unroll
    for (int nt = 0; nt < 4; ++nt)
        #pragma unroll
        for (int ks = 0; ks < 2; ++ks) {
            s16x8 b = *(const s16x8*)(sWl + (lsel * 64 + nt * 16 + (lane & 15)) * 72 +
                                      ks * 32 + (lane >> 4) * 8);
            #pragma unroll
            for (int mt = 0; mt < 2; ++mt)
                acc[mt][nt] = __builtin_amdgcn_mfma_f32_16x16x32_bf16(afr[mt][ks], b,
                                                                      acc[mt][nt], 0, 0, 0);
        }

    // scale by wn and write bf16 to sF
    #pragma unroll
    for (int mt = 0; mt < 2; ++mt)
        #pragma unroll
        for (int nt = 0; nt < 4; ++nt)
            #pragma unroll
            for (int r = 0; r < 4; ++r) {
                int nl = mt * 16 + (lane >> 4) * 4 + r;
                int k = nt * 16 + (lane & 15);
                float scale = sWc[lsel][sElem[nl] * 64 + k];
                sF[m][nl * 72 + k] = f2bf(acc[mt][nt][r] * scale);
            }
    __syncthreads();

    // GEMM2: out_m = f[m] @ W_p{0|1}
    f32x4 acc2[2][4] = {};
    s16x8 af2[2][2];
    #pragma unroll
    for (int mt = 0; mt < 2; ++mt)
        #pragma unroll
        for (int ks = 0; ks < 2; ++ks)
            af2[mt][ks] = *(const s16x8*)(&sF[m][(mt * 16 + (lane & 15)) * 72 +
                                                 ks * 32 + (lane >> 4) * 8]);
    #pragma unroll
    for (int nt = 0; nt < 4; ++nt)
        #pragma unroll
        for (int ks = 0; ks < 2; ++ks) {
            #pragma unroll
            for (int mt = 0; mt < 2; ++mt)
                acc2[mt][nt] = __builtin_amdgcn_mfma_f32_16x16x32_bf16(af2[mt][ks],
                                                                       pf[nt][ks],
                                                                       acc2[mt][nt], 0, 0, 0);
        }

    // epilogue
    #pragma unroll
    for (int mt = 0; mt < 2; ++mt)
        #pragma unroll
        for (int nt = 0; nt < 4; ++nt)
            #pragma unroll
            for (int r = 0; r < 4; ++r) {
                int nl = mt * 16 + (lane >> 4) * 4 + r;
                int k = nt * 16 + (lane & 15);
                size_t nn = (size_t)n0 + nl;
                if (m == 0)
                    out[nn * 256 + k] = acc2[mt][nt][r] + sSc[nl][k];
                else
                    out[nn * 256 + 64 + k * 3 + (m - 1)] = acc2[mt][nt][r];
            }
}

extern "C" void kernel_launch(void* const* d_in, const int* in_sizes, int n_in,
                              void* d_out, int out_size, void* d_ws, size_t ws_size,
                              hipStream_t stream) {
    const float* node_features = (const float*)d_in[0];
    const float* one_hot = (const float*)d_in[1];
    const float* angular = (const float*)d_in[2];
    const float* radial = (const float*)d_in[3];
    const float* W_up = (const float*)d_in[4];
    const float* W_mlp1 = (const float*)d_in[5];
    const float* W_mlp2 = (const float*)d_in[6];
    const float* W_mlp3 = (const float*)d_in[7];
    const float* W_mlp4 = (const float*)d_in[8];
    const float* W_lin = (const float*)d_in[9];
    const float* W_skip = (const float*)d_in[10];
    const float* W_c0 = (const float*)d_in[11];
    const float* W_c1 = (const float*)d_in[12];
    const float* W_p0 = (const float*)d_in[13];
    const float* W_p1 = (const float*)d_in[14];
    const int* edge_index = (const int*)d_in[15];
    float* out = (float*)d_out;

    int N = in_sizes[0] / 64;
    int E = in_sizes[2] / 16;
    const int* sender = edge_index;
    const int* receiver = edge_index + E;

    char* p = (char*)d_ws;
    ushort* x_ws = (ushort*)p;      p += (size_t)N * 64 * 2;
    ushort* tpw = (ushort*)p;       p += (size_t)E * 128 * 2;
    ushort* agg = (ushort*)p;       p += (size_t)N * 256 * 2;
    ushort* wimg = (ushort*)p;      p += 79872 * 2;
    float4* csr_ang = (float4*)p;   p += (size_t)E * 16;
    ushort* csr_radb = (ushort*)p;  p += (size_t)E * 8 * 2;
    int* counts = (int*)p;          p += (size_t)N * 4;
    int* offsets = (int*)p;         p += (size_t)(N + 1) * 4;
    int* cursor = (int*)p;          p += (size_t)N * 4;
    int* csr_sender = (int*)p;      p += (size_t)E * 4;

    hipMemsetAsync(counts, 0, (size_t)N * 4, stream);
    prep_kernel<<<312, 256, 0, stream>>>(W_mlp1, W_mlp2, W_mlp3, W_mlp4,
                                         W_lin, W_p0, W_p1, W_skip, wimg);
    node_up_kernel<<<N / 4, 256, 0, stream>>>(node_features, W_up, x_ws);
    hist_kernel<<<(E + 255) / 256, 256, 0, stream>>>(receiver, counts, E);
    scan_kernel<<<1, 1024, 0, stream>>>(counts, offsets, cursor, N);
    scatter_kernel<<<(E + 255) / 256, 256, 0, stream>>>(receiver, sender, angular,
                                                        radial, cursor, csr_sender,
                                                        csr_ang, csr_radb, E);
    edge_mlp_kernel<<<(E + 127) / 128, 256, 0, stream>>>(csr_radb, wimg, tpw, E);
    agg_kernel<<<(N + 3) / 4, 256, 0, stream>>>(csr_ang, csr_sender, tpw, offsets,
                                                x_ws, agg, N);
    node_out2_kernel<<<N / 32, 256, 0, stream>>>(node_features, one_hot, wimg,
                                                 W_c0, W_c1, agg, out);
}

// Round 6
// 169.807 us; speedup vs baseline: 1.2252x; 1.0175x over previous
//
#include <hip/hip_runtime.h>

typedef __attribute__((ext_vector_type(8))) short s16x8;
typedef __attribute__((ext_vector_type(4))) float f32x4;

__device__ inline float bf2f(ushort u) {
    union { unsigned int i; float f; } v; v.i = ((unsigned)u) << 16; return v.f;
}
__device__ inline ushort f2bf(float f) {
    union { float f; unsigned int i; } v; v.f = f;
    unsigned r = v.i + 0x7FFFu + ((v.i >> 16) & 1u);
    return (ushort)(r >> 16);
}
__device__ inline unsigned cvt_pk(float lo, float hi) {
    unsigned d;
    asm("v_cvt_pk_bf16_f32 %0, %1, %2" : "=v"(d) : "v"(lo), "v"(hi));
    return d;
}
__device__ inline float silu_f(float x) { return x / (1.f + __expf(-x)); }

// K1: x = node_features @ W_up, stored bf16. 4 nodes/block.
__global__ __launch_bounds__(256) void node_up_kernel(const float* __restrict__ nf,
                                                      const float* __restrict__ W_up,
                                                      ushort* __restrict__ x_ws) {
    __shared__ float sW[64 * 64];
    __shared__ float sNf[4][64];
    int tid = threadIdx.x;
    size_t n0 = (size_t)blockIdx.x * 4;
    for (int i = tid; i < 4096; i += 256) sW[i] = W_up[i];
    {
        int r = tid >> 6, c = tid & 63;
        sNf[r][c] = nf[(n0 + r) * 64 + c];
    }
    __syncthreads();
    int r = tid >> 6, k = tid & 63;
    float acc = 0.f;
    #pragma unroll 8
    for (int c = 0; c < 64; ++c) acc += sNf[r][c] * sW[c * 64 + k];
    x_ws[(n0 + r) * 64 + k] = f2bf(acc);
}

// K2: histogram of receivers
__global__ __launch_bounds__(256) void hist_kernel(const int* __restrict__ recv,
                                                   int* __restrict__ counts, int E) {
    int e = blockIdx.x * 256 + threadIdx.x;
    if (e < E) atomicAdd(&counts[recv[e]], 1);
}

// K3: single-pass chunked exclusive scan counts -> offsets (and cursor copy)
__global__ __launch_bounds__(1024) void scan_kernel(const int* __restrict__ counts,
                                                    int* __restrict__ offsets,
                                                    int* __restrict__ cursor, int n) {
    __shared__ int wsums[16];
    int tid = threadIdx.x, lane = tid & 63, wid = tid >> 6;
    int CH = (n + 1023) >> 10;
    int base = tid * CH;
    int tot = 0;
    for (int j = 0; j < CH; ++j) {
        int i = base + j;
        if (i < n) tot += counts[i];
    }
    int v = tot;
    for (int off = 1; off < 64; off <<= 1) {
        int t = __shfl_up(v, off, 64);
        if (lane >= off) v += t;
    }
    if (lane == 63) wsums[wid] = v;
    __syncthreads();
    if (tid == 0) {
        int acc = 0;
        for (int w = 0; w < 16; ++w) { int t = wsums[w]; wsums[w] = acc; acc += t; }
    }
    __syncthreads();
    int excl = wsums[wid] + v - tot;
    for (int j = 0; j < CH; ++j) {
        int i = base + j;
        if (i < n) { offsets[i] = excl; cursor[i] = excl; excl += counts[i]; }
    }
    if (tid == 1023) offsets[n] = excl;
}

// K4: scatter into CSR order: sender, angular(float4 m=0..3), radial(bf16x8)
__global__ __launch_bounds__(256) void scatter_kernel(const int* __restrict__ recv,
                                                      const int* __restrict__ sender,
                                                      const float* __restrict__ angular,
                                                      const float* __restrict__ radial,
                                                      int* __restrict__ cursor,
                                                      int* __restrict__ csr_sender,
                                                      float4* __restrict__ csr_ang,
                                                      ushort* __restrict__ csr_radb, int E) {
    int e = blockIdx.x * 256 + threadIdx.x;
    if (e < E) {
        int r = recv[e];
        int pos = atomicAdd(&cursor[r], 1);
        csr_sender[pos] = sender[e];
        csr_ang[pos] = *(const float4*)(angular + (size_t)e * 16);
        float4 r0 = *(const float4*)(radial + (size_t)e * 8);
        float4 r1 = *(const float4*)(radial + (size_t)e * 8 + 4);
        uint2 lo = {cvt_pk(r0.x, r0.y), cvt_pk(r0.z, r0.w)};
        uint2 hi = {cvt_pk(r1.x, r1.y), cvt_pk(r1.z, r1.w)};
        *(uint2*)(csr_radb + (size_t)pos * 8) = lo;
        *(uint2*)(csr_radb + (size_t)pos * 8 + 4) = hi;
    }
}

// K_prep: bake bf16 weight images + zero the counts array (replaces memset).
// wimg ushort layout:
//   [0,4096)       W1t  (64m x 64k, k<8 real else 0), A-side swizzle
//   [4096,8192)    W2t  (64 x 64)
//   [8192,12288)   W3t  (64 x 64)
//   [12288,20480)  W4t  (128m x 64k)
//   [20480,29696)  wl_img: (l*64+col)*72 + c  = W_lin[l][c][col]
//   [29696,38912)  wp_img: (l*64+col)*72 + c  = W_p{l}[c][col]
//   [38912,79872)  wskb: W_skip bf16 linear (c*10+a)*64+k
__global__ __launch_bounds__(256) void prep_kernel(const float* __restrict__ W1,
                                                   const float* __restrict__ W2,
                                                   const float* __restrict__ W3,
                                                   const float* __restrict__ W4,
                                                   const float* __restrict__ W_lin,
                                                   const float* __restrict__ Wp0,
                                                   const float* __restrict__ Wp1,
                                                   const float* __restrict__ W_skip,
                                                   ushort* __restrict__ wimg,
                                                   int* __restrict__ counts, int N) {
    int idx = blockIdx.x * 256 + threadIdx.x;
    if (idx < N) counts[idx] = 0;
    if (idx < 4096) {
        int m = idx >> 6, k = idx & 63;
        int dst = m * 64 + ((((k >> 3) ^ (m & 7))) << 3) + (k & 7);
        wimg[dst] = (k < 8) ? f2bf(W1[k * 64 + m]) : (ushort)0;
    } else if (idx < 8192) {
        int i = idx - 4096;
        int m = i >> 6, k = i & 63;
        int dst = 4096 + m * 64 + ((((k >> 3) ^ (m & 7))) << 3) + (k & 7);
        wimg[dst] = f2bf(W2[k * 64 + m]);
    } else if (idx < 12288) {
        int i = idx - 8192;
        int m = i >> 6, k = i & 63;
        int dst = 8192 + m * 64 + ((((k >> 3) ^ (m & 7))) << 3) + (k & 7);
        wimg[dst] = f2bf(W3[k * 64 + m]);
    } else if (idx < 20480) {
        int i = idx - 12288;
        int m = i >> 6, k = i & 63;  // m in 0..127
        int dst = 12288 + m * 64 + ((((k >> 3) ^ (m & 7))) << 3) + (k & 7);
        wimg[dst] = f2bf(W4[k * 256 + m]);
    } else if (idx < 29696) {
        int i = idx - 20480;
        int row = i / 72, k = i % 72;
        int l = row >> 6, col = row & 63;
        wimg[idx] = (k < 64) ? f2bf(W_lin[l * 4096 + k * 64 + col]) : (ushort)0;
    } else if (idx < 38912) {
        int i = idx - 29696;
        int row = i / 72, k = i % 72;
        int l = row >> 6, col = row & 63;
        const float* Wp = l ? Wp1 : Wp0;
        wimg[idx] = (k < 64) ? f2bf(Wp[k * 64 + col]) : (ushort)0;
    } else if (idx < 79872) {
        int i = idx - 38912;
        wimg[idx] = f2bf(W_skip[i]);
    }
}

// K5: edge MLP, operand-swapped (D = W^T h^T). 128 edges/block, wave owns 32
// edges (2 subpasses of 16). L4 result stored directly from D-fragments.
__global__ __launch_bounds__(256) void edge_mlp_kernel(const ushort* __restrict__ csr_radb,
                                                       const ushort* __restrict__ wimg,
                                                       ushort* __restrict__ tpw, int E) {
    __shared__ __align__(16) ushort sW4[8192];       // 16KB
    __shared__ __align__(16) ushort sB[4][1024];     // per-wave h bounce, 2KB each
    int tid = threadIdx.x, lane = tid & 63, wave = tid >> 6;
    int n = lane & 15, hi = lane >> 4;

    for (int i = tid; i < 1024; i += 256)
        ((s16x8*)sW4)[i] = ((const s16x8*)(wimg + 12288))[i];

    // preload A-side weight fragments (VGPR-resident, block-invariant)
    s16x8 w1f[4], w2f[4][2], w3f[4][2];
    #pragma unroll
    for (int mt = 0; mt < 4; ++mt) {
        int row = mt * 16 + n, r7 = row & 7;
        w1f[mt] = *(const s16x8*)(wimg + row * 64 + ((hi ^ r7) << 3));
        #pragma unroll
        for (int ks = 0; ks < 2; ++ks) {
            w2f[mt][ks] = *(const s16x8*)(wimg + 4096 + row * 64 + (((ks * 4 + hi) ^ r7) << 3));
            w3f[mt][ks] = *(const s16x8*)(wimg + 8192 + row * 64 + (((ks * 4 + hi) ^ r7) << 3));
        }
    }
    __syncthreads();

    char* myB = (char*)sB[wave];
    int n7 = n & 7;

    for (int sub = 0; sub < 2; ++sub) {
        int base = blockIdx.x * 128 + wave * 32 + sub * 16;
        if (base >= E) break;
        int pos16 = min(base + n, E - 1);

        // radial B-fragment (k = hi*8+j; only k<8 real)
        s16x8 bR;
        #pragma unroll
        for (int j = 0; j < 8; ++j) bR[j] = 0;
        if (hi == 0) bR = *(const s16x8*)(csr_radb + (size_t)pos16 * 8);

        f32x4 zero = {0.f, 0.f, 0.f, 0.f};
        f32x4 d[4];
        // L1 (K=32, zero-padded)
        #pragma unroll
        for (int mt = 0; mt < 4; ++mt)
            d[mt] = __builtin_amdgcn_mfma_f32_16x16x32_bf16(w1f[mt], bR, zero, 0, 0, 0);

        #pragma unroll
        for (int mt = 0; mt < 4; ++mt) {
            uint2 val = {cvt_pk(silu_f(d[mt][0]), silu_f(d[mt][1])),
                         cvt_pk(silu_f(d[mt][2]), silu_f(d[mt][3]))};
            int slot = mt * 2 + (hi >> 1);
            *(uint2*)(myB + n * 128 + ((slot ^ n7) << 4) + (hi & 1) * 8) = val;
        }
        s16x8 b0 = *(const s16x8*)(myB + n * 128 + ((hi ^ n7) << 4));
        s16x8 b1 = *(const s16x8*)(myB + n * 128 + (((4 + hi) ^ n7) << 4));

        // L2
        #pragma unroll
        for (int mt = 0; mt < 4; ++mt) {
            d[mt] = __builtin_amdgcn_mfma_f32_16x16x32_bf16(w2f[mt][0], b0, zero, 0, 0, 0);
            d[mt] = __builtin_amdgcn_mfma_f32_16x16x32_bf16(w2f[mt][1], b1, d[mt], 0, 0, 0);
        }
        #pragma unroll
        for (int mt = 0; mt < 4; ++mt) {
            uint2 val = {cvt_pk(silu_f(d[mt][0]), silu_f(d[mt][1])),
                         cvt_pk(silu_f(d[mt][2]), silu_f(d[mt][3]))};
            int slot = mt * 2 + (hi >> 1);
            *(uint2*)(myB + n * 128 + ((slot ^ n7) << 4) + (hi & 1) * 8) = val;
        }
        b0 = *(const s16x8*)(myB + n * 128 + ((hi ^ n7) << 4));
        b1 = *(const s16x8*)(myB + n * 128 + (((4 + hi) ^ n7) << 4));

        // L3
        #pragma unroll
        for (int mt = 0; mt < 4; ++mt) {
            d[mt] = __builtin_amdgcn_mfma_f32_16x16x32_bf16(w3f[mt][0], b0, zero, 0, 0, 0);
            d[mt] = __builtin_amdgcn_mfma_f32_16x16x32_bf16(w3f[mt][1], b1, d[mt], 0, 0, 0);
        }
        #pragma unroll
        for (int mt = 0; mt < 4; ++mt) {
            uint2 val = {cvt_pk(silu_f(d[mt][0]), silu_f(d[mt][1])),
                         cvt_pk(silu_f(d[mt][2]), silu_f(d[mt][3]))};
            int slot = mt * 2 + (hi >> 1);
            *(uint2*)(myB + n * 128 + ((slot ^ n7) << 4) + (hi & 1) * 8) = val;
        }
        b0 = *(const s16x8*)(myB + n * 128 + ((hi ^ n7) << 4));
        b1 = *(const s16x8*)(myB + n * 128 + (((4 + hi) ^ n7) << 4));

        // L4: 128 outputs (l=0,1), A from LDS sW4; store D-fragments directly.
        bool ok = (base + n) < E;
        size_t rowbase = (size_t)(base + n) * 128;
        #pragma unroll
        for (int mt = 0; mt < 8; ++mt) {
            int row = mt * 16 + n, r7 = row & 7;
            s16x8 a0f = *(const s16x8*)(sW4 + row * 64 + ((hi ^ r7) << 3));
            s16x8 a1f = *(const s16x8*)(sW4 + row * 64 + (((4 + hi) ^ r7) << 3));
            f32x4 o = __builtin_amdgcn_mfma_f32_16x16x32_bf16(a0f, b0, zero, 0, 0, 0);
            o = __builtin_amdgcn_mfma_f32_16x16x32_bf16(a1f, b1, o, 0, 0, 0);
            if (ok) {
                uint2 val = {cvt_pk(o[0], o[1]), cvt_pk(o[2], o[3])};
                *(uint2*)(tpw + rowbase + mt * 16 + hi * 4) = val;
            }
        }
    }
}

// K6a: CSR aggregation. Wave per node, lane = channel, 2-deep x prefetch.
__global__ __launch_bounds__(256) void agg_kernel(const float4* __restrict__ csr_ang,
                                                  const int* __restrict__ csr_sender,
                                                  const ushort* __restrict__ tpw,
                                                  const int* __restrict__ offsets,
                                                  const ushort* __restrict__ x_ws,
                                                  ushort* __restrict__ agg, int N) {
    int wave = threadIdx.x >> 6, lane = threadIdx.x & 63;
    int node = blockIdx.x * 4 + wave;
    if (node >= N) return;
    int beg = offsets[node], end = offsets[node + 1];
    float a0 = 0, a1 = 0, a2 = 0, a3 = 0;
    ushort xa = 0, xb = 0;
    if (beg < end) xa = x_ws[(size_t)csr_sender[beg] * 64 + lane];
    if (beg + 1 < end) xb = x_ws[(size_t)csr_sender[beg + 1] * 64 + lane];
    for (int i = beg; i < end; ++i) {
        ushort xc = 0;
        if (i + 2 < end) xc = x_ws[(size_t)csr_sender[i + 2] * 64 + lane];
        float4 ang = csr_ang[i];
        float tp0 = bf2f(tpw[(size_t)i * 128 + lane]);
        float tp1 = bf2f(tpw[(size_t)i * 128 + 64 + lane]);
        float x = bf2f(xa);
        float y0 = x * tp0, y1 = x * tp1;
        a0 += ang.x * y0;
        a1 += ang.y * y1;
        a2 += ang.z * y1;
        a3 += ang.w * y1;
        xa = xb; xb = xc;
    }
    size_t b = (size_t)node * 256 + lane;
    agg[b] = f2bf(a0 * 0.1f);
    agg[b + 64] = f2bf(a1 * 0.1f);
    agg[b + 128] = f2bf(a2 * 0.1f);
    agg[b + 192] = f2bf(a3 * 0.1f);
}

// K6b: per-32-node tile: feats = agg@W_lin (MFMA), scale by wn, out = f@W_p (+sc0).
__global__ __launch_bounds__(256) void node_out2_kernel(
    const float* __restrict__ nf, const float* __restrict__ one_hot,
    const ushort* __restrict__ wimg, const float* __restrict__ W_c0,
    const float* __restrict__ W_c1, const ushort* __restrict__ agg,
    float* __restrict__ out) {
    __shared__ __align__(16) ushort sWl[2 * 64 * 72];
    __shared__ __align__(16) ushort sF[4][32 * 72];
    __shared__ float sSc[32][64];
    __shared__ float sWc[2][640];
    __shared__ int sElem[32];
    int tid = threadIdx.x;
    int n0 = blockIdx.x * 32;
    int lane = tid & 63, m = tid >> 6;
    int lsel = (m == 0) ? 0 : 1;

    // direct-from-global W_p B-fragments (L2-resident image)
    s16x8 pf[4][2];
    #pragma unroll
    for (int nt = 0; nt < 4; ++nt)
        #pragma unroll
        for (int ks = 0; ks < 2; ++ks)
            pf[nt][ks] = *(const s16x8*)(wimg + 29696 +
                (lsel * 64 + nt * 16 + (lane & 15)) * 72 + ks * 32 + (lane >> 4) * 8);

    for (int i = tid; i < 1152; i += 256)
        ((s16x8*)sWl)[i] = ((const s16x8*)(wimg + 20480))[i];
    for (int i = tid; i < 1280; i += 256)
        sWc[i >= 640][i % 640] = (i >= 640 ? W_c1 : W_c0)[i % 640];
    if (tid < 32) {
        int nn = n0 + tid, e = 0;
        for (int a = 0; a < 10; ++a)
            if (one_hot[(size_t)nn * 10 + a] > 0.5f) { e = a; break; }
        sElem[tid] = e;
    }
    __syncthreads();

    // sc0 skip connection: 8 threads per node, 8 k's per thread, bf16 W_skip
    {
        int nl = tid >> 3, k0 = (tid & 7) * 8;
        int nn = n0 + nl, elem = sElem[nl];
        float acc[8] = {0, 0, 0, 0, 0, 0, 0, 0};
        const ushort* wskb = wimg + 38912;
        for (int c = 0; c < 64; ++c) {
            float v = nf[(size_t)nn * 64 + c];
            s16x8 w = *(const s16x8*)(wskb + ((size_t)c * 10 + elem) * 64 + k0);
            #pragma unroll
            for (int j = 0; j < 8; ++j) acc[j] += v * bf2f((ushort)w[j]);
        }
        #pragma unroll
        for (int j = 0; j < 8; ++j) sSc[nl][k0 + j] = acc[j];
    }

    // GEMM1: feats[m] = agg[:,m,:] @ W_lin[lsel]   (M=32, K=64, N=64)
    f32x4 acc[2][4] = {};
    s16x8 afr[2][2];
    #pragma unroll
    for (int mt = 0; mt < 2; ++mt)
        #pragma unroll
        for (int ks = 0; ks < 2; ++ks)
            afr[mt][ks] = *(const s16x8*)(agg +
                (((size_t)(n0 + mt * 16 + (lane & 15))) * 4 + m) * 64 +
                ks * 32 + (lane >> 4) * 8);
    #pragma unroll
    for (int nt = 0; nt < 4; ++nt)
        #pragma unroll
        for (int ks = 0; ks < 2; ++ks) {
            s16x8 b = *(const s16x8*)(sWl + (lsel * 64 + nt * 16 + (lane & 15)) * 72 +
                                      ks * 32 + (lane >> 4) * 8);
            #pragma unroll
            for (int mt = 0; mt < 2; ++mt)
                acc[mt][nt] = __builtin_amdgcn_mfma_f32_16x16x32_bf16(afr[mt][ks], b,
                                                                      acc[mt][nt], 0, 0, 0);
        }

    // scale by wn and write bf16 to sF
    #pragma unroll
    for (int mt = 0; mt < 2; ++mt)
        #pragma unroll
        for (int nt = 0; nt < 4; ++nt)
            #pragma unroll
            for (int r = 0; r < 4; ++r) {
                int nl = mt * 16 + (lane >> 4) * 4 + r;
                int k = nt * 16 + (lane & 15);
                float scale = sWc[lsel][sElem[nl] * 64 + k];
                sF[m][nl * 72 + k] = f2bf(acc[mt][nt][r] * scale);
            }
    __syncthreads();

    // GEMM2: out_m = f[m] @ W_p{0|1}
    f32x4 acc2[2][4] = {};
    s16x8 af2[2][2];
    #pragma unroll
    for (int mt = 0; mt < 2; ++mt)
        #pragma unroll
        for (int ks = 0; ks < 2; ++ks)
            af2[mt][ks] = *(const s16x8*)(&sF[m][(mt * 16 + (lane & 15)) * 72 +
                                                 ks * 32 + (lane >> 4) * 8]);
    #pragma unroll
    for (int nt = 0; nt < 4; ++nt)
        #pragma unroll
        for (int ks = 0; ks < 2; ++ks) {
            #pragma unroll
            for (int mt = 0; mt < 2; ++mt)
                acc2[mt][nt] = __builtin_amdgcn_mfma_f32_16x16x32_bf16(af2[mt][ks],
                                                                       pf[nt][ks],
                                                                       acc2[mt][nt], 0, 0, 0);
        }

    // epilogue
    #pragma unroll
    for (int mt = 0; mt < 2; ++mt)
        #pragma unroll
        for (int nt = 0; nt < 4; ++nt)
            #pragma unroll
            for (int r = 0; r < 4; ++r) {
                int nl = mt * 16 + (lane >> 4) * 4 + r;
                int k = nt * 16 + (lane & 15);
                size_t nn = (size_t)n0 + nl;
                if (m == 0)
                    out[nn * 256 + k] = acc2[mt][nt][r] + sSc[nl][k];
                else
                    out[nn * 256 + 64 + k * 3 + (m - 1)] = acc2[mt][nt][r];
            }
}

extern "C" void kernel_launch(void* const* d_in, const int* in_sizes, int n_in,
                              void* d_out, int out_size, void* d_ws, size_t ws_size,
                              hipStream_t stream) {
    const float* node_features = (const float*)d_in[0];
    const float* one_hot = (const float*)d_in[1];
    const float* angular = (const float*)d_in[2];
    const float* radial = (const float*)d_in[3];
    const float* W_up = (const float*)d_in[4];
    const float* W_mlp1 = (const float*)d_in[5];
    const float* W_mlp2 = (const float*)d_in[6];
    const float* W_mlp3 = (const float*)d_in[7];
    const float* W_mlp4 = (const float*)d_in[8];
    const float* W_lin = (const float*)d_in[9];
    const float* W_skip = (const float*)d_in[10];
    const float* W_c0 = (const float*)d_in[11];
    const float* W_c1 = (const float*)d_in[12];
    const float* W_p0 = (const float*)d_in[13];
    const float* W_p1 = (const float*)d_in[14];
    const int* edge_index = (const int*)d_in[15];
    float* out = (float*)d_out;

    int N = in_sizes[0] / 64;
    int E = in_sizes[2] / 16;
    const int* sender = edge_index;
    const int* receiver = edge_index + E;

    char* p = (char*)d_ws;
    ushort* x_ws = (ushort*)p;      p += (size_t)N * 64 * 2;
    ushort* tpw = (ushort*)p;       p += (size_t)E * 128 * 2;
    ushort* agg = (ushort*)p;       p += (size_t)N * 256 * 2;
    ushort* wimg = (ushort*)p;      p += 79872 * 2;
    float4* csr_ang = (float4*)p;   p += (size_t)E * 16;
    ushort* csr_radb = (ushort*)p;  p += (size_t)E * 8 * 2;
    int* counts = (int*)p;          p += (size_t)N * 4;
    int* offsets = (int*)p;         p += (size_t)(N + 1) * 4;
    int* cursor = (int*)p;          p += (size_t)N * 4;
    int* csr_sender = (int*)p;      p += (size_t)E * 4;

    prep_kernel<<<312, 256, 0, stream>>>(W_mlp1, W_mlp2, W_mlp3, W_mlp4,
                                         W_lin, W_p0, W_p1, W_skip, wimg,
                                         counts, N);
    node_up_kernel<<<N / 4, 256, 0, stream>>>(node_features, W_up, x_ws);
    hist_kernel<<<(E + 255) / 256, 256, 0, stream>>>(receiver, counts, E);
    scan_kernel<<<1, 1024, 0, stream>>>(counts, offsets, cursor, N);
    scatter_kernel<<<(E + 255) / 256, 256, 0, stream>>>(receiver, sender, angular,
                                                        radial, cursor, csr_sender,
                                                        csr_ang, csr_radb, E);
    edge_mlp_kernel<<<(E + 127) / 128, 256, 0, stream>>>(csr_radb, wimg, tpw, E);
    agg_kernel<<<(N + 3) / 4, 256, 0, stream>>>(csr_ang, csr_sender, tpw, offsets,
                                                x_ws, agg, N);
    node_out2_kernel<<<N / 32, 256, 0, stream>>>(node_features, one_hot, wimg,
                                                 W_c0, W_c1, agg, out);
}

// Round 7
// 157.947 us; speedup vs baseline: 1.3172x; 1.0751x over previous
//
#include <hip/hip_runtime.h>

typedef __attribute__((ext_vector_type(8))) short s16x8;
typedef __attribute__((ext_vector_type(4))) float f32x4;

__device__ inline float bf2f(ushort u) {
    union { unsigned int i; float f; } v; v.i = ((unsigned)u) << 16; return v.f;
}
__device__ inline float u2f(unsigned u) {
    union { unsigned int i; float f; } v; v.i = u; return v.f;
}
__device__ inline ushort f2bf(float f) {
    union { float f; unsigned int i; } v; v.f = f;
    unsigned r = v.i + 0x7FFFu + ((v.i >> 16) & 1u);
    return (ushort)(r >> 16);
}
__device__ inline unsigned cvt_pk(float lo, float hi) {
    unsigned d;
    asm("v_cvt_pk_bf16_f32 %0, %1, %2" : "=v"(d) : "v"(lo), "v"(hi));
    return d;
}
__device__ inline float silu_f(float x) { return x / (1.f + __expf(-x)); }

// K1 merged: blocks [0, N/4) do node_up; blocks [N/4, N/4+312) do prep+counts-zero.
// wimg ushort layout:
//   [0,4096)       W1t  (64m x 64k, k<8 real else 0), A-side swizzle
//   [4096,8192)    W2t  (64 x 64)
//   [8192,12288)   W3t  (64 x 64)
//   [12288,20480)  W4t  (128m x 64k)
//   [20480,29696)  wl_img: (l*64+col)*72 + c  = W_lin[l][c][col]
//   [29696,38912)  wp_img: (l*64+col)*72 + c  = W_p{l}[c][col]
//   [38912,79872)  wskb: W_skip bf16 linear (c*10+a)*64+k
__global__ __launch_bounds__(256) void prep_up_kernel(
    const float* __restrict__ nf, const float* __restrict__ W_up,
    ushort* __restrict__ x_ws,
    const float* __restrict__ W1, const float* __restrict__ W2,
    const float* __restrict__ W3, const float* __restrict__ W4,
    const float* __restrict__ W_lin, const float* __restrict__ Wp0,
    const float* __restrict__ Wp1, const float* __restrict__ W_skip,
    ushort* __restrict__ wimg, int* __restrict__ counts, int N) {
    __shared__ float sW[64 * 64];
    __shared__ float sNf[4][64];
    int tid = threadIdx.x;
    int nub = N / 4;
    if ((int)blockIdx.x < nub) {
        size_t n0 = (size_t)blockIdx.x * 4;
        for (int i = tid; i < 4096; i += 256) sW[i] = W_up[i];
        {
            int r = tid >> 6, c = tid & 63;
            sNf[r][c] = nf[(n0 + r) * 64 + c];
        }
        __syncthreads();
        int r = tid >> 6, k = tid & 63;
        float acc = 0.f;
        #pragma unroll 8
        for (int c = 0; c < 64; ++c) acc += sNf[r][c] * sW[c * 64 + k];
        x_ws[(n0 + r) * 64 + k] = f2bf(acc);
        return;
    }
    int idx = ((int)blockIdx.x - nub) * 256 + tid;
    if (idx < N) counts[idx] = 0;
    if (idx < 4096) {
        int m = idx >> 6, k = idx & 63;
        int dst = m * 64 + ((((k >> 3) ^ (m & 7))) << 3) + (k & 7);
        wimg[dst] = (k < 8) ? f2bf(W1[k * 64 + m]) : (ushort)0;
    } else if (idx < 8192) {
        int i = idx - 4096;
        int m = i >> 6, k = i & 63;
        int dst = 4096 + m * 64 + ((((k >> 3) ^ (m & 7))) << 3) + (k & 7);
        wimg[dst] = f2bf(W2[k * 64 + m]);
    } else if (idx < 12288) {
        int i = idx - 8192;
        int m = i >> 6, k = i & 63;
        int dst = 8192 + m * 64 + ((((k >> 3) ^ (m & 7))) << 3) + (k & 7);
        wimg[dst] = f2bf(W3[k * 64 + m]);
    } else if (idx < 20480) {
        int i = idx - 12288;
        int m = i >> 6, k = i & 63;  // m in 0..127
        int dst = 12288 + m * 64 + ((((k >> 3) ^ (m & 7))) << 3) + (k & 7);
        wimg[dst] = f2bf(W4[k * 256 + m]);
    } else if (idx < 29696) {
        int i = idx - 20480;
        int row = i / 72, k = i % 72;
        int l = row >> 6, col = row & 63;
        wimg[idx] = (k < 64) ? f2bf(W_lin[l * 4096 + k * 64 + col]) : (ushort)0;
    } else if (idx < 38912) {
        int i = idx - 29696;
        int row = i / 72, k = i % 72;
        int l = row >> 6, col = row & 63;
        const float* Wp = l ? Wp1 : Wp0;
        wimg[idx] = (k < 64) ? f2bf(Wp[k * 64 + col]) : (ushort)0;
    } else if (idx < 79872) {
        int i = idx - 38912;
        wimg[idx] = f2bf(W_skip[i]);
    }
}

// K2: histogram of receivers
__global__ __launch_bounds__(256) void hist_kernel(const int* __restrict__ recv,
                                                   int* __restrict__ counts, int E) {
    int e = blockIdx.x * 256 + threadIdx.x;
    if (e < E) atomicAdd(&counts[recv[e]], 1);
}

// K3: single-pass chunked exclusive scan counts -> offsets (and cursor copy)
__global__ __launch_bounds__(1024) void scan_kernel(const int* __restrict__ counts,
                                                    int* __restrict__ offsets,
                                                    int* __restrict__ cursor, int n) {
    __shared__ int wsums[16];
    int tid = threadIdx.x, lane = tid & 63, wid = tid >> 6;
    int CH = (n + 1023) >> 10;
    int base = tid * CH;
    int tot = 0;
    for (int j = 0; j < CH; ++j) {
        int i = base + j;
        if (i < n) tot += counts[i];
    }
    int v = tot;
    for (int off = 1; off < 64; off <<= 1) {
        int t = __shfl_up(v, off, 64);
        if (lane >= off) v += t;
    }
    if (lane == 63) wsums[wid] = v;
    __syncthreads();
    if (tid == 0) {
        int acc = 0;
        for (int w = 0; w < 16; ++w) { int t = wsums[w]; wsums[w] = acc; acc += t; }
    }
    __syncthreads();
    int excl = wsums[wid] + v - tot;
    for (int j = 0; j < CH; ++j) {
        int i = base + j;
        if (i < n) { offsets[i] = excl; cursor[i] = excl; excl += counts[i]; }
    }
    if (tid == 1023) offsets[n] = excl;
}

// K4: scatter into CSR order: sender, angular(float4 m=0..3), radial(bf16x8)
__global__ __launch_bounds__(256) void scatter_kernel(const int* __restrict__ recv,
                                                      const int* __restrict__ sender,
                                                      const float* __restrict__ angular,
                                                      const float* __restrict__ radial,
                                                      int* __restrict__ cursor,
                                                      int* __restrict__ csr_sender,
                                                      float4* __restrict__ csr_ang,
                                                      ushort* __restrict__ csr_radb, int E) {
    int e = blockIdx.x * 256 + threadIdx.x;
    if (e < E) {
        int r = recv[e];
        int pos = atomicAdd(&cursor[r], 1);
        csr_sender[pos] = sender[e];
        csr_ang[pos] = *(const float4*)(angular + (size_t)e * 16);
        float4 r0 = *(const float4*)(radial + (size_t)e * 8);
        float4 r1 = *(const float4*)(radial + (size_t)e * 8 + 4);
        uint2 lo = {cvt_pk(r0.x, r0.y), cvt_pk(r0.z, r0.w)};
        uint2 hi = {cvt_pk(r1.x, r1.y), cvt_pk(r1.z, r1.w)};
        *(uint2*)(csr_radb + (size_t)pos * 8) = lo;
        *(uint2*)(csr_radb + (size_t)pos * 8 + 4) = hi;
    }
}

// K5: edge MLP, operand-swapped (D = W^T h^T). 128 edges/block, wave owns 32
// edges (2 subpasses of 16). L4 stored as uint32-packed (l0|l1<<16) per channel.
__global__ __launch_bounds__(256) void edge_mlp_kernel(const ushort* __restrict__ csr_radb,
                                                       const ushort* __restrict__ wimg,
                                                       unsigned* __restrict__ tpw32, int E) {
    __shared__ __align__(16) ushort sW4[8192];       // 16KB
    __shared__ __align__(16) ushort sB[4][1024];     // per-wave h bounce, 2KB each
    int tid = threadIdx.x, lane = tid & 63, wave = tid >> 6;
    int n = lane & 15, hi = lane >> 4;

    for (int i = tid; i < 1024; i += 256)
        ((s16x8*)sW4)[i] = ((const s16x8*)(wimg + 12288))[i];

    // preload A-side weight fragments (VGPR-resident, block-invariant)
    s16x8 w1f[4], w2f[4][2], w3f[4][2];
    #pragma unroll
    for (int mt = 0; mt < 4; ++mt) {
        int row = mt * 16 + n, r7 = row & 7;
        w1f[mt] = *(const s16x8*)(wimg + row * 64 + ((hi ^ r7) << 3));
        #pragma unroll
        for (int ks = 0; ks < 2; ++ks) {
            w2f[mt][ks] = *(const s16x8*)(wimg + 4096 + row * 64 + (((ks * 4 + hi) ^ r7) << 3));
            w3f[mt][ks] = *(const s16x8*)(wimg + 8192 + row * 64 + (((ks * 4 + hi) ^ r7) << 3));
        }
    }
    __syncthreads();

    char* myB = (char*)sB[wave];
    int n7 = n & 7;

    for (int sub = 0; sub < 2; ++sub) {
        int base = blockIdx.x * 128 + wave * 32 + sub * 16;
        if (base >= E) break;
        int pos16 = min(base + n, E - 1);

        // radial B-fragment (k = hi*8+j; only k<8 real)
        s16x8 bR;
        #pragma unroll
        for (int j = 0; j < 8; ++j) bR[j] = 0;
        if (hi == 0) bR = *(const s16x8*)(csr_radb + (size_t)pos16 * 8);

        f32x4 zero = {0.f, 0.f, 0.f, 0.f};
        f32x4 d[4];
        // L1 (K=32, zero-padded)
        #pragma unroll
        for (int mt = 0; mt < 4; ++mt)
            d[mt] = __builtin_amdgcn_mfma_f32_16x16x32_bf16(w1f[mt], bR, zero, 0, 0, 0);

        #pragma unroll
        for (int mt = 0; mt < 4; ++mt) {
            uint2 val = {cvt_pk(silu_f(d[mt][0]), silu_f(d[mt][1])),
                         cvt_pk(silu_f(d[mt][2]), silu_f(d[mt][3]))};
            int slot = mt * 2 + (hi >> 1);
            *(uint2*)(myB + n * 128 + ((slot ^ n7) << 4) + (hi & 1) * 8) = val;
        }
        s16x8 b0 = *(const s16x8*)(myB + n * 128 + ((hi ^ n7) << 4));
        s16x8 b1 = *(const s16x8*)(myB + n * 128 + (((4 + hi) ^ n7) << 4));

        // L2
        #pragma unroll
        for (int mt = 0; mt < 4; ++mt) {
            d[mt] = __builtin_amdgcn_mfma_f32_16x16x32_bf16(w2f[mt][0], b0, zero, 0, 0, 0);
            d[mt] = __builtin_amdgcn_mfma_f32_16x16x32_bf16(w2f[mt][1], b1, d[mt], 0, 0, 0);
        }
        #pragma unroll
        for (int mt = 0; mt < 4; ++mt) {
            uint2 val = {cvt_pk(silu_f(d[mt][0]), silu_f(d[mt][1])),
                         cvt_pk(silu_f(d[mt][2]), silu_f(d[mt][3]))};
            int slot = mt * 2 + (hi >> 1);
            *(uint2*)(myB + n * 128 + ((slot ^ n7) << 4) + (hi & 1) * 8) = val;
        }
        b0 = *(const s16x8*)(myB + n * 128 + ((hi ^ n7) << 4));
        b1 = *(const s16x8*)(myB + n * 128 + (((4 + hi) ^ n7) << 4));

        // L3
        #pragma unroll
        for (int mt = 0; mt < 4; ++mt) {
            d[mt] = __builtin_amdgcn_mfma_f32_16x16x32_bf16(w3f[mt][0], b0, zero, 0, 0, 0);
            d[mt] = __builtin_amdgcn_mfma_f32_16x16x32_bf16(w3f[mt][1], b1, d[mt], 0, 0, 0);
        }
        #pragma unroll
        for (int mt = 0; mt < 4; ++mt) {
            uint2 val = {cvt_pk(silu_f(d[mt][0]), silu_f(d[mt][1])),
                         cvt_pk(silu_f(d[mt][2]), silu_f(d[mt][3]))};
            int slot = mt * 2 + (hi >> 1);
            *(uint2*)(myB + n * 128 + ((slot ^ n7) << 4) + (hi & 1) * 8) = val;
        }
        b0 = *(const s16x8*)(myB + n * 128 + ((hi ^ n7) << 4));
        b1 = *(const s16x8*)(myB + n * 128 + (((4 + hi) ^ n7) << 4));

        // L4: 128 outputs (l=0,1), A from LDS sW4; pack (l0,l1) pairs per channel.
        f32x4 o[8];
        #pragma unroll
        for (int mt = 0; mt < 8; ++mt) {
            int row = mt * 16 + n, r7 = row & 7;
            s16x8 a0f = *(const s16x8*)(sW4 + row * 64 + ((hi ^ r7) << 3));
            s16x8 a1f = *(const s16x8*)(sW4 + row * 64 + (((4 + hi) ^ r7) << 3));
            o[mt] = __builtin_amdgcn_mfma_f32_16x16x32_bf16(a0f, b0, zero, 0, 0, 0);
            o[mt] = __builtin_amdgcn_mfma_f32_16x16x32_bf16(a1f, b1, o[mt], 0, 0, 0);
        }
        if ((base + n) < E) {
            size_t rowbase = (size_t)(base + n) * 64;
            #pragma unroll
            for (int mt = 0; mt < 4; ++mt) {
                uint4 val;
                val.x = cvt_pk(o[mt][0], o[mt + 4][0]);
                val.y = cvt_pk(o[mt][1], o[mt + 4][1]);
                val.z = cvt_pk(o[mt][2], o[mt + 4][2]);
                val.w = cvt_pk(o[mt][3], o[mt + 4][3]);
                *(uint4*)(tpw32 + rowbase + mt * 16 + hi * 4) = val;
            }
        }
    }
}

// K6a: CSR aggregation. Wave per node, lane = channel. Senders lane-preloaded
// per 64-edge chunk + __shfl; 2-deep x prefetch; packed tp (1 uint/lane/edge).
__global__ __launch_bounds__(256) void agg_kernel(const float4* __restrict__ csr_ang,
                                                  const int* __restrict__ csr_sender,
                                                  const unsigned* __restrict__ tpw32,
                                                  const int* __restrict__ offsets,
                                                  const ushort* __restrict__ x_ws,
                                                  ushort* __restrict__ agg, int N) {
    int wave = threadIdx.x >> 6, lane = threadIdx.x & 63;
    int node = blockIdx.x * 4 + wave;
    if (node >= N) return;
    int beg = offsets[node], end = offsets[node + 1];
    float a0 = 0, a1 = 0, a2 = 0, a3 = 0;
    for (int cb = beg; cb < end; cb += 64) {
        int m = min(64, end - cb);
        int sv = csr_sender[cb + min(lane, m - 1)];
        ushort xa = x_ws[(size_t)__shfl(sv, 0) * 64 + lane];
        ushort xb = (m > 1) ? x_ws[(size_t)__shfl(sv, 1) * 64 + lane] : (ushort)0;
        for (int e = 0; e < m; ++e) {
            ushort xc = (e + 2 < m) ? x_ws[(size_t)__shfl(sv, e + 2) * 64 + lane]
                                    : (ushort)0;
            float4 ang = csr_ang[cb + e];
            unsigned t = tpw32[(size_t)(cb + e) * 64 + lane];
            float x = bf2f(xa);
            float tp0 = u2f(t << 16);
            float tp1 = u2f(t & 0xffff0000u);
            float y0 = x * tp0, y1 = x * tp1;
            a0 += ang.x * y0;
            a1 += ang.y * y1;
            a2 += ang.z * y1;
            a3 += ang.w * y1;
            xa = xb; xb = xc;
        }
    }
    size_t b = (size_t)node * 256 + lane;
    agg[b] = f2bf(a0 * 0.1f);
    agg[b + 64] = f2bf(a1 * 0.1f);
    agg[b + 128] = f2bf(a2 * 0.1f);
    agg[b + 192] = f2bf(a3 * 0.1f);
}

// K6b: per-32-node tile: feats = agg@W_lin (MFMA), scale by wn, out = f@W_p (+sc0).
__global__ __launch_bounds__(256) void node_out2_kernel(
    const float* __restrict__ nf, const float* __restrict__ one_hot,
    const ushort* __restrict__ wimg, const float* __restrict__ W_c0,
    const float* __restrict__ W_c1, const ushort* __restrict__ agg,
    float* __restrict__ out) {
    __shared__ __align__(16) ushort sWl[2 * 64 * 72];
    __shared__ __align__(16) ushort sF[4][32 * 72];
    __shared__ float sSc[32][64];
    __shared__ float sWc[2][640];
    __shared__ int sElem[32];
    int tid = threadIdx.x;
    int n0 = blockIdx.x * 32;
    int lane = tid & 63, m = tid >> 6;
    int lsel = (m == 0) ? 0 : 1;

    // direct-from-global W_p B-fragments (L2-resident image)
    s16x8 pf[4][2];
    #pragma unroll
    for (int nt = 0; nt < 4; ++nt)
        #pragma unroll
        for (int ks = 0; ks < 2; ++ks)
            pf[nt][ks] = *(const s16x8*)(wimg + 29696 +
                (lsel * 64 + nt * 16 + (lane & 15)) * 72 + ks * 32 + (lane >> 4) * 8);

    for (int i = tid; i < 1152; i += 256)
        ((s16x8*)sWl)[i] = ((const s16x8*)(wimg + 20480))[i];
    for (int i = tid; i < 1280; i += 256)
        sWc[i >= 640][i % 640] = (i >= 640 ? W_c1 : W_c0)[i % 640];
    if (tid < 32) {
        int nn = n0 + tid, e = 0;
        for (int a = 0; a < 10; ++a)
            if (one_hot[(size_t)nn * 10 + a] > 0.5f) { e = a; break; }
        sElem[tid] = e;
    }
    __syncthreads();

    // sc0 skip connection: 8 threads per node, 8 k's per thread, bf16 W_skip
    {
        int nl = tid >> 3, k0 = (tid & 7) * 8;
        int nn = n0 + nl, elem = sElem[nl];
        float acc[8] = {0, 0, 0, 0, 0, 0, 0, 0};
        const ushort* wskb = wimg + 38912;
        for (int c = 0; c < 64; ++c) {
            float v = nf[(size_t)nn * 64 + c];
            s16x8 w = *(const s16x8*)(wskb + ((size_t)c * 10 + elem) * 64 + k0);
            #pragma unroll
            for (int j = 0; j < 8; ++j) acc[j] += v * bf2f((ushort)w[j]);
        }
        #pragma unroll
        for (int j = 0; j < 8; ++j) sSc[nl][k0 + j] = acc[j];
    }

    // GEMM1: feats[m] = agg[:,m,:] @ W_lin[lsel]   (M=32, K=64, N=64)
    f32x4 acc[2][4] = {};
    s16x8 afr[2][2];
    #pragma unroll
    for (int mt = 0; mt < 2; ++mt)
        #pragma unroll
        for (int ks = 0; ks < 2; ++ks)
            afr[mt][ks] = *(const s16x8*)(agg +
                (((size_t)(n0 + mt * 16 + (lane & 15))) * 4 + m) * 64 +
                ks * 32 + (lane >> 4) * 8);
    #pragma unroll
    for (int nt = 0; nt < 4; ++nt)
        #pragma unroll
        for (int ks = 0; ks < 2; ++ks) {
            s16x8 b = *(const s16x8*)(sWl + (lsel * 64 + nt * 16 + (lane & 15)) * 72 +
                                      ks * 32 + (lane >> 4) * 8);
            #pragma unroll
            for (int mt = 0; mt < 2; ++mt)
                acc[mt][nt] = __builtin_amdgcn_mfma_f32_16x16x32_bf16(afr[mt][ks], b,
                                                                      acc[mt][nt], 0, 0, 0);
        }

    // scale by wn and write bf16 to sF
    #pragma unroll
    for (int mt = 0; mt < 2; ++mt)
        #pragma unroll
        for (int nt = 0; nt < 4; ++nt)
            #pragma unroll
            for (int r = 0; r < 4; ++r) {
                int nl = mt * 16 + (lane >> 4) * 4 + r;
                int k = nt * 16 + (lane & 15);
                float scale = sWc[lsel][sElem[nl] * 64 + k];
                sF[m][nl * 72 + k] = f2bf(acc[mt][nt][r] * scale);
            }
    __syncthreads();

    // GEMM2: out_m = f[m] @ W_p{0|1}
    f32x4 acc2[2][4] = {};
    s16x8 af2[2][2];
    #pragma unroll
    for (int mt = 0; mt < 2; ++mt)
        #pragma unroll
        for (int ks = 0; ks < 2; ++ks)
            af2[mt][ks] = *(const s16x8*)(&sF[m][(mt * 16 + (lane & 15)) * 72 +
                                                 ks * 32 + (lane >> 4) * 8]);
    #pragma unroll
    for (int nt = 0; nt < 4; ++nt)
        #pragma unroll
        for (int ks = 0; ks < 2; ++ks) {
            #pragma unroll
            for (int mt = 0; mt < 2; ++mt)
                acc2[mt][nt] = __builtin_amdgcn_mfma_f32_16x16x32_bf16(af2[mt][ks],
                                                                       pf[nt][ks],
                                                                       acc2[mt][nt], 0, 0, 0);
        }

    // epilogue
    #pragma unroll
    for (int mt = 0; mt < 2; ++mt)
        #pragma unroll
        for (int nt = 0; nt < 4; ++nt)
            #pragma unroll
            for (int r = 0; r < 4; ++r) {
                int nl = mt * 16 + (lane >> 4) * 4 + r;
                int k = nt * 16 + (lane & 15);
                size_t nn = (size_t)n0 + nl;
                if (m == 0)
                    out[nn * 256 + k] = acc2[mt][nt][r] + sSc[nl][k];
                else
                    out[nn * 256 + 64 + k * 3 + (m - 1)] = acc2[mt][nt][r];
            }
}

extern "C" void kernel_launch(void* const* d_in, const int* in_sizes, int n_in,
                              void* d_out, int out_size, void* d_ws, size_t ws_size,
                              hipStream_t stream) {
    const float* node_features = (const float*)d_in[0];
    const float* one_hot = (const float*)d_in[1];
    const float* angular = (const float*)d_in[2];
    const float* radial = (const float*)d_in[3];
    const float* W_up = (const float*)d_in[4];
    const float* W_mlp1 = (const float*)d_in[5];
    const float* W_mlp2 = (const float*)d_in[6];
    const float* W_mlp3 = (const float*)d_in[7];
    const float* W_mlp4 = (const float*)d_in[8];
    const float* W_lin = (const float*)d_in[9];
    const float* W_skip = (const float*)d_in[10];
    const float* W_c0 = (const float*)d_in[11];
    const float* W_c1 = (const float*)d_in[12];
    const float* W_p0 = (const float*)d_in[13];
    const float* W_p1 = (const float*)d_in[14];
    const int* edge_index = (const int*)d_in[15];
    float* out = (float*)d_out;

    int N = in_sizes[0] / 64;
    int E = in_sizes[2] / 16;
    const int* sender = edge_index;
    const int* receiver = edge_index + E;

    char* p = (char*)d_ws;
    ushort* x_ws = (ushort*)p;      p += (size_t)N * 64 * 2;
    unsigned* tpw32 = (unsigned*)p; p += (size_t)E * 64 * 4;
    ushort* agg = (ushort*)p;       p += (size_t)N * 256 * 2;
    ushort* wimg = (ushort*)p;      p += 79872 * 2;
    float4* csr_ang = (float4*)p;   p += (size_t)E * 16;
    ushort* csr_radb = (ushort*)p;  p += (size_t)E * 8 * 2;
    int* counts = (int*)p;          p += (size_t)N * 4;
    int* offsets = (int*)p;         p += (size_t)(N + 1) * 4;
    int* cursor = (int*)p;          p += (size_t)N * 4;
    int* csr_sender = (int*)p;      p += (size_t)E * 4;

    prep_up_kernel<<<N / 4 + 312, 256, 0, stream>>>(node_features, W_up, x_ws,
                                                    W_mlp1, W_mlp2, W_mlp3, W_mlp4,
                                                    W_lin, W_p0, W_p1, W_skip, wimg,
                                                    counts, N);
    hist_kernel<<<(E + 255) / 256, 256, 0, stream>>>(receiver, counts, E);
    scan_kernel<<<1, 1024, 0, stream>>>(counts, offsets, cursor, N);
    scatter_kernel<<<(E + 255) / 256, 256, 0, stream>>>(receiver, sender, angular,
                                                        radial, cursor, csr_sender,
                                                        csr_ang, csr_radb, E);
    edge_mlp_kernel<<<(E + 127) / 128, 256, 0, stream>>>(csr_radb, wimg, tpw32, E);
    agg_kernel<<<(N + 3) / 4, 256, 0, stream>>>(csr_ang, csr_sender, tpw32, offsets,
                                                x_ws, agg, N);
    node_out2_kernel<<<N / 32, 256, 0, stream>>>(node_features, one_hot, wimg,
                                                 W_c0, W_c1, agg, out);
}

// Round 8
// 150.380 us; speedup vs baseline: 1.3835x; 1.0503x over previous
//
#include <hip/hip_runtime.h>

typedef __attribute__((ext_vector_type(8))) short s16x8;
typedef __attribute__((ext_vector_type(4))) float f32x4;

__device__ inline float bf2f(ushort u) {
    union { unsigned int i; float f; } v; v.i = ((unsigned)u) << 16; return v.f;
}
__device__ inline float u2f(unsigned u) {
    union { unsigned int i; float f; } v; v.i = u; return v.f;
}
__device__ inline ushort f2bf(float f) {
    union { float f; unsigned int i; } v; v.f = f;
    unsigned r = v.i + 0x7FFFu + ((v.i >> 16) & 1u);
    return (ushort)(r >> 16);
}
__device__ inline unsigned cvt_pk(float lo, float hi) {
    unsigned d;
    asm("v_cvt_pk_bf16_f32 %0, %1, %2" : "=v"(d) : "v"(lo), "v"(hi));
    return d;
}
__device__ inline float silu_f(float x) { return x / (1.f + __expf(-x)); }

// K1 merged: blocks [0, N/4) do node_up; blocks [N/4, N/4+312) do prep+counts-zero.
// wimg ushort layout:
//   [0,4096)       W1t  (64m x 64k, k<8 real else 0), A-side swizzle
//   [4096,8192)    W2t  (64 x 64)
//   [8192,12288)   W3t  (64 x 64)
//   [12288,20480)  W4t  (128m x 64k)
//   [20480,29696)  wl_img: (l*64+col)*72 + c  = W_lin[l][c][col]
//   [29696,38912)  wp_img: (l*64+col)*72 + c  = W_p{l}[c][col]
//   [38912,79872)  wskb: W_skip bf16 linear (c*10+a)*64+k
__global__ __launch_bounds__(256) void prep_up_kernel(
    const float* __restrict__ nf, const float* __restrict__ W_up,
    ushort* __restrict__ x_ws,
    const float* __restrict__ W1, const float* __restrict__ W2,
    const float* __restrict__ W3, const float* __restrict__ W4,
    const float* __restrict__ W_lin, const float* __restrict__ Wp0,
    const float* __restrict__ Wp1, const float* __restrict__ W_skip,
    ushort* __restrict__ wimg, int* __restrict__ counts, int N) {
    __shared__ float sW[64 * 64];
    __shared__ float sNf[4][64];
    int tid = threadIdx.x;
    int nub = N / 4;
    if ((int)blockIdx.x < nub) {
        size_t n0 = (size_t)blockIdx.x * 4;
        for (int i = tid; i < 4096; i += 256) sW[i] = W_up[i];
        {
            int r = tid >> 6, c = tid & 63;
            sNf[r][c] = nf[(n0 + r) * 64 + c];
        }
        __syncthreads();
        int r = tid >> 6, k = tid & 63;
        float acc = 0.f;
        #pragma unroll 8
        for (int c = 0; c < 64; ++c) acc += sNf[r][c] * sW[c * 64 + k];
        x_ws[(n0 + r) * 64 + k] = f2bf(acc);
        return;
    }
    int idx = ((int)blockIdx.x - nub) * 256 + tid;
    if (idx < N) counts[idx] = 0;
    if (idx < 4096) {
        int m = idx >> 6, k = idx & 63;
        int dst = m * 64 + ((((k >> 3) ^ (m & 7))) << 3) + (k & 7);
        wimg[dst] = (k < 8) ? f2bf(W1[k * 64 + m]) : (ushort)0;
    } else if (idx < 8192) {
        int i = idx - 4096;
        int m = i >> 6, k = i & 63;
        int dst = 4096 + m * 64 + ((((k >> 3) ^ (m & 7))) << 3) + (k & 7);
        wimg[dst] = f2bf(W2[k * 64 + m]);
    } else if (idx < 12288) {
        int i = idx - 8192;
        int m = i >> 6, k = i & 63;
        int dst = 8192 + m * 64 + ((((k >> 3) ^ (m & 7))) << 3) + (k & 7);
        wimg[dst] = f2bf(W3[k * 64 + m]);
    } else if (idx < 20480) {
        int i = idx - 12288;
        int m = i >> 6, k = i & 63;  // m in 0..127
        int dst = 12288 + m * 64 + ((((k >> 3) ^ (m & 7))) << 3) + (k & 7);
        wimg[dst] = f2bf(W4[k * 256 + m]);
    } else if (idx < 29696) {
        int i = idx - 20480;
        int row = i / 72, k = i % 72;
        int l = row >> 6, col = row & 63;
        wimg[idx] = (k < 64) ? f2bf(W_lin[l * 4096 + k * 64 + col]) : (ushort)0;
    } else if (idx < 38912) {
        int i = idx - 29696;
        int row = i / 72, k = i % 72;
        int l = row >> 6, col = row & 63;
        const float* Wp = l ? Wp1 : Wp0;
        wimg[idx] = (k < 64) ? f2bf(Wp[k * 64 + col]) : (ushort)0;
    } else if (idx < 79872) {
        int i = idx - 38912;
        wimg[idx] = f2bf(W_skip[i]);
    }
}

// K2: histogram of receivers
__global__ __launch_bounds__(256) void hist_kernel(const int* __restrict__ recv,
                                                   int* __restrict__ counts, int E) {
    int e = blockIdx.x * 256 + threadIdx.x;
    if (e < E) atomicAdd(&counts[recv[e]], 1);
}

// K3: single-pass chunked exclusive scan counts -> offsets (and cursor copy)
__global__ __launch_bounds__(1024) void scan_kernel(const int* __restrict__ counts,
                                                    int* __restrict__ offsets,
                                                    int* __restrict__ cursor, int n) {
    __shared__ int wsums[16];
    int tid = threadIdx.x, lane = tid & 63, wid = tid >> 6;
    int CH = (n + 1023) >> 10;
    int base = tid * CH;
    int tot = 0;
    for (int j = 0; j < CH; ++j) {
        int i = base + j;
        if (i < n) tot += counts[i];
    }
    int v = tot;
    for (int off = 1; off < 64; off <<= 1) {
        int t = __shfl_up(v, off, 64);
        if (lane >= off) v += t;
    }
    if (lane == 63) wsums[wid] = v;
    __syncthreads();
    if (tid == 0) {
        int acc = 0;
        for (int w = 0; w < 16; ++w) { int t = wsums[w]; wsums[w] = acc; acc += t; }
    }
    __syncthreads();
    int excl = wsums[wid] + v - tot;
    for (int j = 0; j < CH; ++j) {
        int i = base + j;
        if (i < n) { offsets[i] = excl; cursor[i] = excl; excl += counts[i]; }
    }
    if (tid == 1023) offsets[n] = excl;
}

// K4: scatter into CSR order: sender, angular(float4 m=0..3), radial(bf16x8)
__global__ __launch_bounds__(256) void scatter_kernel(const int* __restrict__ recv,
                                                      const int* __restrict__ sender,
                                                      const float* __restrict__ angular,
                                                      const float* __restrict__ radial,
                                                      int* __restrict__ cursor,
                                                      int* __restrict__ csr_sender,
                                                      float4* __restrict__ csr_ang,
                                                      ushort* __restrict__ csr_radb, int E) {
    int e = blockIdx.x * 256 + threadIdx.x;
    if (e < E) {
        int r = recv[e];
        int pos = atomicAdd(&cursor[r], 1);
        csr_sender[pos] = sender[e];
        csr_ang[pos] = *(const float4*)(angular + (size_t)e * 16);
        float4 r0 = *(const float4*)(radial + (size_t)e * 8);
        float4 r1 = *(const float4*)(radial + (size_t)e * 8 + 4);
        uint2 lo = {cvt_pk(r0.x, r0.y), cvt_pk(r0.z, r0.w)};
        uint2 hi = {cvt_pk(r1.x, r1.y), cvt_pk(r1.z, r1.w)};
        *(uint2*)(csr_radb + (size_t)pos * 8) = lo;
        *(uint2*)(csr_radb + (size_t)pos * 8 + 4) = hi;
    }
}

// K5: edge MLP, operand-swapped (D = W^T h^T). 128 edges/block, wave owns 32
// edges (2 subpasses of 16). L4 stored as uint32-packed (l0|l1<<16) per channel.
__global__ __launch_bounds__(256) void edge_mlp_kernel(const ushort* __restrict__ csr_radb,
                                                       const ushort* __restrict__ wimg,
                                                       unsigned* __restrict__ tpw32, int E) {
    __shared__ __align__(16) ushort sW4[8192];       // 16KB
    __shared__ __align__(16) ushort sB[4][1024];     // per-wave h bounce, 2KB each
    int tid = threadIdx.x, lane = tid & 63, wave = tid >> 6;
    int n = lane & 15, hi = lane >> 4;

    for (int i = tid; i < 1024; i += 256)
        ((s16x8*)sW4)[i] = ((const s16x8*)(wimg + 12288))[i];

    // preload A-side weight fragments (VGPR-resident, block-invariant)
    s16x8 w1f[4], w2f[4][2], w3f[4][2];
    #pragma unroll
    for (int mt = 0; mt < 4; ++mt) {
        int row = mt * 16 + n, r7 = row & 7;
        w1f[mt] = *(const s16x8*)(wimg + row * 64 + ((hi ^ r7) << 3));
        #pragma unroll
        for (int ks = 0; ks < 2; ++ks) {
            w2f[mt][ks] = *(const s16x8*)(wimg + 4096 + row * 64 + (((ks * 4 + hi) ^ r7) << 3));
            w3f[mt][ks] = *(const s16x8*)(wimg + 8192 + row * 64 + (((ks * 4 + hi) ^ r7) << 3));
        }
    }
    __syncthreads();

    char* myB = (char*)sB[wave];
    int n7 = n & 7;

    for (int sub = 0; sub < 2; ++sub) {
        int base = blockIdx.x * 128 + wave * 32 + sub * 16;
        if (base >= E) break;
        int pos16 = min(base + n, E - 1);

        // radial B-fragment (k = hi*8+j; only k<8 real)
        s16x8 bR;
        #pragma unroll
        for (int j = 0; j < 8; ++j) bR[j] = 0;
        if (hi == 0) bR = *(const s16x8*)(csr_radb + (size_t)pos16 * 8);

        f32x4 zero = {0.f, 0.f, 0.f, 0.f};
        f32x4 d[4];
        // L1 (K=32, zero-padded)
        #pragma unroll
        for (int mt = 0; mt < 4; ++mt)
            d[mt] = __builtin_amdgcn_mfma_f32_16x16x32_bf16(w1f[mt], bR, zero, 0, 0, 0);

        #pragma unroll
        for (int mt = 0; mt < 4; ++mt) {
            uint2 val = {cvt_pk(silu_f(d[mt][0]), silu_f(d[mt][1])),
                         cvt_pk(silu_f(d[mt][2]), silu_f(d[mt][3]))};
            int slot = mt * 2 + (hi >> 1);
            *(uint2*)(myB + n * 128 + ((slot ^ n7) << 4) + (hi & 1) * 8) = val;
        }
        s16x8 b0 = *(const s16x8*)(myB + n * 128 + ((hi ^ n7) << 4));
        s16x8 b1 = *(const s16x8*)(myB + n * 128 + (((4 + hi) ^ n7) << 4));

        // L2
        #pragma unroll
        for (int mt = 0; mt < 4; ++mt) {
            d[mt] = __builtin_amdgcn_mfma_f32_16x16x32_bf16(w2f[mt][0], b0, zero, 0, 0, 0);
            d[mt] = __builtin_amdgcn_mfma_f32_16x16x32_bf16(w2f[mt][1], b1, d[mt], 0, 0, 0);
        }
        #pragma unroll
        for (int mt = 0; mt < 4; ++mt) {
            uint2 val = {cvt_pk(silu_f(d[mt][0]), silu_f(d[mt][1])),
                         cvt_pk(silu_f(d[mt][2]), silu_f(d[mt][3]))};
            int slot = mt * 2 + (hi >> 1);
            *(uint2*)(myB + n * 128 + ((slot ^ n7) << 4) + (hi & 1) * 8) = val;
        }
        b0 = *(const s16x8*)(myB + n * 128 + ((hi ^ n7) << 4));
        b1 = *(const s16x8*)(myB + n * 128 + (((4 + hi) ^ n7) << 4));

        // L3
        #pragma unroll
        for (int mt = 0; mt < 4; ++mt) {
            d[mt] = __builtin_amdgcn_mfma_f32_16x16x32_bf16(w3f[mt][0], b0, zero, 0, 0, 0);
            d[mt] = __builtin_amdgcn_mfma_f32_16x16x32_bf16(w3f[mt][1], b1, d[mt], 0, 0, 0);
        }
        #pragma unroll
        for (int mt = 0; mt < 4; ++mt) {
            uint2 val = {cvt_pk(silu_f(d[mt][0]), silu_f(d[mt][1])),
                         cvt_pk(silu_f(d[mt][2]), silu_f(d[mt][3]))};
            int slot = mt * 2 + (hi >> 1);
            *(uint2*)(myB + n * 128 + ((slot ^ n7) << 4) + (hi & 1) * 8) = val;
        }
        b0 = *(const s16x8*)(myB + n * 128 + ((hi ^ n7) << 4));
        b1 = *(const s16x8*)(myB + n * 128 + (((4 + hi) ^ n7) << 4));

        // L4: 128 outputs (l=0,1), A from LDS sW4; pack (l0,l1) pairs per channel.
        f32x4 o[8];
        #pragma unroll
        for (int mt = 0; mt < 8; ++mt) {
            int row = mt * 16 + n, r7 = row & 7;
            s16x8 a0f = *(const s16x8*)(sW4 + row * 64 + ((hi ^ r7) << 3));
            s16x8 a1f = *(const s16x8*)(sW4 + row * 64 + (((4 + hi) ^ r7) << 3));
            o[mt] = __builtin_amdgcn_mfma_f32_16x16x32_bf16(a0f, b0, zero, 0, 0, 0);
            o[mt] = __builtin_amdgcn_mfma_f32_16x16x32_bf16(a1f, b1, o[mt], 0, 0, 0);
        }
        if ((base + n) < E) {
            size_t rowbase = (size_t)(base + n) * 64;
            #pragma unroll
            for (int mt = 0; mt < 4; ++mt) {
                uint4 val;
                val.x = cvt_pk(o[mt][0], o[mt + 4][0]);
                val.y = cvt_pk(o[mt][1], o[mt + 4][1]);
                val.z = cvt_pk(o[mt][2], o[mt + 4][2]);
                val.w = cvt_pk(o[mt][3], o[mt + 4][3]);
                *(uint4*)(tpw32 + rowbase + mt * 16 + hi * 4) = val;
            }
        }
    }
}

// K6a: CSR aggregation. Wave per node, lane = channel. 4-edge batched loads:
// issue 12 independent loads (t,x,ang ×4) then consume — hides L2 latency.
__global__ __launch_bounds__(256) void agg_kernel(const float4* __restrict__ csr_ang,
                                                  const int* __restrict__ csr_sender,
                                                  const unsigned* __restrict__ tpw32,
                                                  const int* __restrict__ offsets,
                                                  const ushort* __restrict__ x_ws,
                                                  ushort* __restrict__ agg, int N) {
    int wave = threadIdx.x >> 6, lane = threadIdx.x & 63;
    int node = blockIdx.x * 4 + wave;
    if (node >= N) return;
    int beg = offsets[node], end = offsets[node + 1];
    float a0 = 0, a1 = 0, a2 = 0, a3 = 0;
    for (int cb = beg; cb < end; cb += 64) {
        int m = min(64, end - cb);
        int sv = csr_sender[cb + min(lane, m - 1)];
        for (int e0 = 0; e0 < m; e0 += 4) {
            unsigned t[4];
            ushort x[4];
            float4 g[4];
            #pragma unroll
            for (int j = 0; j < 4; ++j) {
                int e = e0 + j;
                int ec = min(e, m - 1);
                t[j] = tpw32[(size_t)(cb + ec) * 64 + lane];
                x[j] = x_ws[(size_t)__shfl(sv, ec) * 64 + lane];
                if (e < m) g[j] = csr_ang[cb + e];
                else g[j] = make_float4(0.f, 0.f, 0.f, 0.f);
            }
            #pragma unroll
            for (int j = 0; j < 4; ++j) {
                float xv = bf2f(x[j]);
                float tp0 = u2f(t[j] << 16);
                float tp1 = u2f(t[j] & 0xffff0000u);
                float y0 = xv * tp0, y1 = xv * tp1;
                a0 += g[j].x * y0;
                a1 += g[j].y * y1;
                a2 += g[j].z * y1;
                a3 += g[j].w * y1;
            }
        }
    }
    size_t b = (size_t)node * 256 + lane;
    agg[b] = f2bf(a0 * 0.1f);
    agg[b + 64] = f2bf(a1 * 0.1f);
    agg[b + 128] = f2bf(a2 * 0.1f);
    agg[b + 192] = f2bf(a3 * 0.1f);
}

// K6b: per-32-node tile: feats = agg@W_lin (MFMA), scale by wn, out = f@W_p (+sc0).
__global__ __launch_bounds__(256) void node_out2_kernel(
    const float* __restrict__ nf, const float* __restrict__ one_hot,
    const ushort* __restrict__ wimg, const float* __restrict__ W_c0,
    const float* __restrict__ W_c1, const ushort* __restrict__ agg,
    float* __restrict__ out) {
    __shared__ __align__(16) ushort sWl[2 * 64 * 72];
    __shared__ __align__(16) ushort sF[4][32 * 72];
    __shared__ float sSc[32][64];
    __shared__ float sWc[2][640];
    __shared__ int sElem[32];
    int tid = threadIdx.x;
    int n0 = blockIdx.x * 32;
    int lane = tid & 63, m = tid >> 6;
    int lsel = (m == 0) ? 0 : 1;

    // direct-from-global W_p B-fragments (L2-resident image)
    s16x8 pf[4][2];
    #pragma unroll
    for (int nt = 0; nt < 4; ++nt)
        #pragma unroll
        for (int ks = 0; ks < 2; ++ks)
            pf[nt][ks] = *(const s16x8*)(wimg + 29696 +
                (lsel * 64 + nt * 16 + (lane & 15)) * 72 + ks * 32 + (lane >> 4) * 8);

    for (int i = tid; i < 1152; i += 256)
        ((s16x8*)sWl)[i] = ((const s16x8*)(wimg + 20480))[i];
    for (int i = tid; i < 1280; i += 256)
        sWc[i >= 640][i % 640] = (i >= 640 ? W_c1 : W_c0)[i % 640];
    if (tid < 32) {
        int nn = n0 + tid, e = 0;
        for (int a = 0; a < 10; ++a)
            if (one_hot[(size_t)nn * 10 + a] > 0.5f) { e = a; break; }
        sElem[tid] = e;
    }
    __syncthreads();

    // sc0 skip connection: 8 threads per node, 8 k's per thread, bf16 W_skip
    {
        int nl = tid >> 3, k0 = (tid & 7) * 8;
        int nn = n0 + nl, elem = sElem[nl];
        float acc[8] = {0, 0, 0, 0, 0, 0, 0, 0};
        const ushort* wskb = wimg + 38912;
        for (int c = 0; c < 64; ++c) {
            float v = nf[(size_t)nn * 64 + c];
            s16x8 w = *(const s16x8*)(wskb + ((size_t)c * 10 + elem) * 64 + k0);
            #pragma unroll
            for (int j = 0; j < 8; ++j) acc[j] += v * bf2f((ushort)w[j]);
        }
        #pragma unroll
        for (int j = 0; j < 8; ++j) sSc[nl][k0 + j] = acc[j];
    }

    // GEMM1: feats[m] = agg[:,m,:] @ W_lin[lsel]   (M=32, K=64, N=64)
    f32x4 acc[2][4] = {};
    s16x8 afr[2][2];
    #pragma unroll
    for (int mt = 0; mt < 2; ++mt)
        #pragma unroll
        for (int ks = 0; ks < 2; ++ks)
            afr[mt][ks] = *(const s16x8*)(agg +
                (((size_t)(n0 + mt * 16 + (lane & 15))) * 4 + m) * 64 +
                ks * 32 + (lane >> 4) * 8);
    #pragma unroll
    for (int nt = 0; nt < 4; ++nt)
        #pragma unroll
        for (int ks = 0; ks < 2; ++ks) {
            s16x8 b = *(const s16x8*)(sWl + (lsel * 64 + nt * 16 + (lane & 15)) * 72 +
                                      ks * 32 + (lane >> 4) * 8);
            #pragma unroll
            for (int mt = 0; mt < 2; ++mt)
                acc[mt][nt] = __builtin_amdgcn_mfma_f32_16x16x32_bf16(afr[mt][ks], b,
                                                                      acc[mt][nt], 0, 0, 0);
        }

    // scale by wn and write bf16 to sF
    #pragma unroll
    for (int mt = 0; mt < 2; ++mt)
        #pragma unroll
        for (int nt = 0; nt < 4; ++nt)
            #pragma unroll
            for (int r = 0; r < 4; ++r) {
                int nl = mt * 16 + (lane >> 4) * 4 + r;
                int k = nt * 16 + (lane & 15);
                float scale = sWc[lsel][sElem[nl] * 64 + k];
                sF[m][nl * 72 + k] = f2bf(acc[mt][nt][r] * scale);
            }
    __syncthreads();

    // GEMM2: out_m = f[m] @ W_p{0|1}
    f32x4 acc2[2][4] = {};
    s16x8 af2[2][2];
    #pragma unroll
    for (int mt = 0; mt < 2; ++mt)
        #pragma unroll
        for (int ks = 0; ks < 2; ++ks)
            af2[mt][ks] = *(const s16x8*)(&sF[m][(mt * 16 + (lane & 15)) * 72 +
                                                 ks * 32 + (lane >> 4) * 8]);
    #pragma unroll
    for (int nt = 0; nt < 4; ++nt)
        #pragma unroll
        for (int ks = 0; ks < 2; ++ks) {
            #pragma unroll
            for (int mt = 0; mt < 2; ++mt)
                acc2[mt][nt] = __builtin_amdgcn_mfma_f32_16x16x32_bf16(af2[mt][ks],
                                                                       pf[nt][ks],
                                                                       acc2[mt][nt], 0, 0, 0);
        }

    // epilogue
    #pragma unroll
    for (int mt = 0; mt < 2; ++mt)
        #pragma unroll
        for (int nt = 0; nt < 4; ++nt)
            #pragma unroll
            for (int r = 0; r < 4; ++r) {
                int nl = mt * 16 + (lane >> 4) * 4 + r;
                int k = nt * 16 + (lane & 15);
                size_t nn = (size_t)n0 + nl;
                if (m == 0)
                    out[nn * 256 + k] = acc2[mt][nt][r] + sSc[nl][k];
                else
                    out[nn * 256 + 64 + k * 3 + (m - 1)] = acc2[mt][nt][r];
            }
}

extern "C" void kernel_launch(void* const* d_in, const int* in_sizes, int n_in,
                              void* d_out, int out_size, void* d_ws, size_t ws_size,
                              hipStream_t stream) {
    const float* node_features = (const float*)d_in[0];
    const float* one_hot = (const float*)d_in[1];
    const float* angular = (const float*)d_in[2];
    const float* radial = (const float*)d_in[3];
    const float* W_up = (const float*)d_in[4];
    const float* W_mlp1 = (const float*)d_in[5];
    const float* W_mlp2 = (const float*)d_in[6];
    const float* W_mlp3 = (const float*)d_in[7];
    const float* W_mlp4 = (const float*)d_in[8];
    const float* W_lin = (const float*)d_in[9];
    const float* W_skip = (const float*)d_in[10];
    const float* W_c0 = (const float*)d_in[11];
    const float* W_c1 = (const float*)d_in[12];
    const float* W_p0 = (const float*)d_in[13];
    const float* W_p1 = (const float*)d_in[14];
    const int* edge_index = (const int*)d_in[15];
    float* out = (float*)d_out;

    int N = in_sizes[0] / 64;
    int E = in_sizes[2] / 16;
    const int* sender = edge_index;
    const int* receiver = edge_index + E;

    char* p = (char*)d_ws;
    ushort* x_ws = (ushort*)p;      p += (size_t)N * 64 * 2;
    unsigned* tpw32 = (unsigned*)p; p += (size_t)E * 64 * 4;
    ushort* agg = (ushort*)p;       p += (size_t)N * 256 * 2;
    ushort* wimg = (ushort*)p;      p += 79872 * 2;
    float4* csr_ang = (float4*)p;   p += (size_t)E * 16;
    ushort* csr_radb = (ushort*)p;  p += (size_t)E * 8 * 2;
    int* counts = (int*)p;          p += (size_t)N * 4;
    int* offsets = (int*)p;         p += (size_t)(N + 1) * 4;
    int* cursor = (int*)p;          p += (size_t)N * 4;
    int* csr_sender = (int*)p;      p += (size_t)E * 4;

    prep_up_kernel<<<N / 4 + 312, 256, 0, stream>>>(node_features, W_up, x_ws,
                                                    W_mlp1, W_mlp2, W_mlp3, W_mlp4,
                                                    W_lin, W_p0, W_p1, W_skip, wimg,
                                                    counts, N);
    hist_kernel<<<(E + 255) / 256, 256, 0, stream>>>(receiver, counts, E);
    scan_kernel<<<1, 1024, 0, stream>>>(counts, offsets, cursor, N);
    scatter_kernel<<<(E + 255) / 256, 256, 0, stream>>>(receiver, sender, angular,
                                                        radial, cursor, csr_sender,
                                                        csr_ang, csr_radb, E);
    edge_mlp_kernel<<<(E + 127) / 128, 256, 0, stream>>>(csr_radb, wimg, tpw32, E);
    agg_kernel<<<(N + 3) / 4, 256, 0, stream>>>(csr_ang, csr_sender, tpw32, offsets,
                                                x_ws, agg, N);
    node_out2_kernel<<<N / 32, 256, 0, stream>>>(node_features, one_hot, wimg,
                                                 W_c0, W_c1, agg, out);
}

// Round 9
// 129.594 us; speedup vs baseline: 1.6054x; 1.1604x over previous
//
#include <hip/hip_runtime.h>

typedef __attribute__((ext_vector_type(8))) short s16x8;
typedef __attribute__((ext_vector_type(4))) float f32x4;

__device__ inline float bf2f(ushort u) {
    union { unsigned int i; float f; } v; v.i = ((unsigned)u) << 16; return v.f;
}
__device__ inline float u2f(unsigned u) {
    union { unsigned int i; float f; } v; v.i = u; return v.f;
}
__device__ inline ushort f2bf(float f) {
    union { float f; unsigned int i; } v; v.f = f;
    unsigned r = v.i + 0x7FFFu + ((v.i >> 16) & 1u);
    return (ushort)(r >> 16);
}
__device__ inline unsigned cvt_pk(float lo, float hi) {
    unsigned d;
    asm("v_cvt_pk_bf16_f32 %0, %1, %2" : "=v"(d) : "v"(lo), "v"(hi));
    return d;
}
// fast silu: x * rcp(1 + 2^(-x*log2e)) — 5 VALU ops, correct at +-inf
__device__ inline float silu_f(float x) {
    float e;
    asm("v_exp_f32 %0, %1" : "=v"(e) : "v"(x * -1.44269504f));
    float d = 1.f + e, r;
    asm("v_rcp_f32 %0, %1" : "=v"(r) : "v"(d));
    return x * r;
}

// K1 merged: blocks [0, N/32) do node_up (32 nodes/block); rest do prep+counts.
// wimg ushort layout:
//   [0,4096)       W1t  (64m x 64k, k<8 real else 0), A-side swizzle
//   [4096,8192)    W2t  (64 x 64)
//   [8192,12288)   W3t  (64 x 64)
//   [12288,20480)  W4t  (128m x 64k)
//   [20480,29696)  wl_img: (l*64+col)*72 + c  = W_lin[l][c][col]
//   [29696,38912)  wp_img: (l*64+col)*72 + c  = W_p{l}[c][col]
//   [38912,79872)  wskb: W_skip bf16 linear (c*10+a)*64+k
__global__ __launch_bounds__(256) void prep_up_kernel(
    const float* __restrict__ nf, const float* __restrict__ W_up,
    ushort* __restrict__ x_ws,
    const float* __restrict__ W1, const float* __restrict__ W2,
    const float* __restrict__ W3, const float* __restrict__ W4,
    const float* __restrict__ W_lin, const float* __restrict__ Wp0,
    const float* __restrict__ Wp1, const float* __restrict__ W_skip,
    ushort* __restrict__ wimg, int* __restrict__ counts, int N) {
    __shared__ float sW[64 * 64];
    __shared__ float sNf[32][64];
    int tid = threadIdx.x;
    int nub = N / 32;
    if ((int)blockIdx.x < nub) {
        size_t n0 = (size_t)blockIdx.x * 32;
        for (int i = tid; i < 4096; i += 256) sW[i] = W_up[i];
        for (int i = tid; i < 2048; i += 256) {
            int r = i >> 6, c = i & 63;
            sNf[r][c] = nf[(n0 + r) * 64 + c];
        }
        __syncthreads();
        int r = tid >> 3, k0 = (tid & 7) * 8;
        float acc[8] = {0, 0, 0, 0, 0, 0, 0, 0};
        #pragma unroll 4
        for (int c = 0; c < 64; ++c) {
            float v = sNf[r][c];
            const float* wr = &sW[c * 64 + k0];
            #pragma unroll
            for (int j = 0; j < 8; ++j) acc[j] += v * wr[j];
        }
        uint4 val;
        val.x = cvt_pk(acc[0], acc[1]);
        val.y = cvt_pk(acc[2], acc[3]);
        val.z = cvt_pk(acc[4], acc[5]);
        val.w = cvt_pk(acc[6], acc[7]);
        *(uint4*)(x_ws + (n0 + r) * 64 + k0) = val;
        return;
    }
    int idx = ((int)blockIdx.x - nub) * 256 + tid;
    if (idx < N) counts[idx] = 0;
    if (idx < 4096) {
        int m = idx >> 6, k = idx & 63;
        int dst = m * 64 + ((((k >> 3) ^ (m & 7))) << 3) + (k & 7);
        wimg[dst] = (k < 8) ? f2bf(W1[k * 64 + m]) : (ushort)0;
    } else if (idx < 8192) {
        int i = idx - 4096;
        int m = i >> 6, k = i & 63;
        int dst = 4096 + m * 64 + ((((k >> 3) ^ (m & 7))) << 3) + (k & 7);
        wimg[dst] = f2bf(W2[k * 64 + m]);
    } else if (idx < 12288) {
        int i = idx - 8192;
        int m = i >> 6, k = i & 63;
        int dst = 8192 + m * 64 + ((((k >> 3) ^ (m & 7))) << 3) + (k & 7);
        wimg[dst] = f2bf(W3[k * 64 + m]);
    } else if (idx < 20480) {
        int i = idx - 12288;
        int m = i >> 6, k = i & 63;  // m in 0..127
        int dst = 12288 + m * 64 + ((((k >> 3) ^ (m & 7))) << 3) + (k & 7);
        wimg[dst] = f2bf(W4[k * 256 + m]);
    } else if (idx < 29696) {
        int i = idx - 20480;
        int row = i / 72, k = i % 72;
        int l = row >> 6, col = row & 63;
        wimg[idx] = (k < 64) ? f2bf(W_lin[l * 4096 + k * 64 + col]) : (ushort)0;
    } else if (idx < 38912) {
        int i = idx - 29696;
        int row = i / 72, k = i % 72;
        int l = row >> 6, col = row & 63;
        const float* Wp = l ? Wp1 : Wp0;
        wimg[idx] = (k < 64) ? f2bf(Wp[k * 64 + col]) : (ushort)0;
    } else if (idx < 79872) {
        int i = idx - 38912;
        wimg[idx] = f2bf(W_skip[i]);
    }
}

// K2: histogram of receivers
__global__ __launch_bounds__(256) void hist_kernel(const int* __restrict__ recv,
                                                   int* __restrict__ counts, int E) {
    int e = blockIdx.x * 256 + threadIdx.x;
    if (e < E) atomicAdd(&counts[recv[e]], 1);
}

// K3: single-pass chunked exclusive scan counts -> offsets (and cursor copy)
__global__ __launch_bounds__(1024) void scan_kernel(const int* __restrict__ counts,
                                                    int* __restrict__ offsets,
                                                    int* __restrict__ cursor, int n) {
    __shared__ int wsums[16];
    int tid = threadIdx.x, lane = tid & 63, wid = tid >> 6;
    int CH = (n + 1023) >> 10;
    int base = tid * CH;
    int cnt[20];
    int tot = 0;
    if (CH <= 20) {
        #pragma unroll
        for (int j = 0; j < 20; ++j) {
            int i = base + j;
            cnt[j] = (j < CH && i < n) ? counts[i] : 0;
            tot += cnt[j];
        }
    } else {
        for (int j = 0; j < CH; ++j) {
            int i = base + j;
            if (i < n) tot += counts[i];
        }
    }
    int v = tot;
    for (int off = 1; off < 64; off <<= 1) {
        int t = __shfl_up(v, off, 64);
        if (lane >= off) v += t;
    }
    if (lane == 63) wsums[wid] = v;
    __syncthreads();
    if (tid == 0) {
        int acc = 0;
        for (int w = 0; w < 16; ++w) { int t = wsums[w]; wsums[w] = acc; acc += t; }
    }
    __syncthreads();
    int excl = wsums[wid] + v - tot;
    if (CH <= 20) {
        #pragma unroll
        for (int j = 0; j < 20; ++j) {
            int i = base + j;
            if (j < CH && i < n) {
                offsets[i] = excl; cursor[i] = excl; excl += cnt[j];
            }
        }
    } else {
        for (int j = 0; j < CH; ++j) {
            int i = base + j;
            if (i < n) { offsets[i] = excl; cursor[i] = excl; excl += counts[i]; }
        }
    }
    if (tid == 1023) offsets[n] = excl;
}

// K4: scatter into CSR order: sender, angular(float4 m=0..3), radial(bf16x8)
__global__ __launch_bounds__(256) void scatter_kernel(const int* __restrict__ recv,
                                                      const int* __restrict__ sender,
                                                      const float* __restrict__ angular,
                                                      const float* __restrict__ radial,
                                                      int* __restrict__ cursor,
                                                      int* __restrict__ csr_sender,
                                                      float4* __restrict__ csr_ang,
                                                      ushort* __restrict__ csr_radb, int E) {
    int e = blockIdx.x * 256 + threadIdx.x;
    if (e < E) {
        int r = recv[e];
        int pos = atomicAdd(&cursor[r], 1);
        csr_sender[pos] = sender[e];
        csr_ang[pos] = *(const float4*)(angular + (size_t)e * 16);
        float4 r0 = *(const float4*)(radial + (size_t)e * 8);
        float4 r1 = *(const float4*)(radial + (size_t)e * 8 + 4);
        uint2 lo = {cvt_pk(r0.x, r0.y), cvt_pk(r0.z, r0.w)};
        uint2 hi = {cvt_pk(r1.x, r1.y), cvt_pk(r1.z, r1.w)};
        *(uint2*)(csr_radb + (size_t)pos * 8) = lo;
        *(uint2*)(csr_radb + (size_t)pos * 8 + 4) = hi;
    }
}

// K5: edge MLP, operand-swapped (D = W^T h^T). 128 edges/block, wave owns 32
// edges (2 subpasses of 16). L4 stored as uint32-packed (l0|l1<<16) per channel.
__global__ __launch_bounds__(256) void edge_mlp_kernel(const ushort* __restrict__ csr_radb,
                                                       const ushort* __restrict__ wimg,
                                                       unsigned* __restrict__ tpw32, int E) {
    __shared__ __align__(16) ushort sW4[8192];       // 16KB
    __shared__ __align__(16) ushort sB[4][1024];     // per-wave h bounce, 2KB each
    int tid = threadIdx.x, lane = tid & 63, wave = tid >> 6;
    int n = lane & 15, hi = lane >> 4;

    for (int i = tid; i < 1024; i += 256)
        ((s16x8*)sW4)[i] = ((const s16x8*)(wimg + 12288))[i];

    // preload A-side weight fragments (VGPR-resident, block-invariant)
    s16x8 w1f[4], w2f[4][2], w3f[4][2];
    #pragma unroll
    for (int mt = 0; mt < 4; ++mt) {
        int row = mt * 16 + n, r7 = row & 7;
        w1f[mt] = *(const s16x8*)(wimg + row * 64 + ((hi ^ r7) << 3));
        #pragma unroll
        for (int ks = 0; ks < 2; ++ks) {
            w2f[mt][ks] = *(const s16x8*)(wimg + 4096 + row * 64 + (((ks * 4 + hi) ^ r7) << 3));
            w3f[mt][ks] = *(const s16x8*)(wimg + 8192 + row * 64 + (((ks * 4 + hi) ^ r7) << 3));
        }
    }
    __syncthreads();

    char* myB = (char*)sB[wave];
    int n7 = n & 7;

    for (int sub = 0; sub < 2; ++sub) {
        int base = blockIdx.x * 128 + wave * 32 + sub * 16;
        if (base >= E) break;
        int pos16 = min(base + n, E - 1);

        // radial B-fragment (k = hi*8+j; only k<8 real)
        s16x8 bR;
        #pragma unroll
        for (int j = 0; j < 8; ++j) bR[j] = 0;
        if (hi == 0) bR = *(const s16x8*)(csr_radb + (size_t)pos16 * 8);

        f32x4 zero = {0.f, 0.f, 0.f, 0.f};
        f32x4 d[4];
        // L1 (K=32, zero-padded)
        #pragma unroll
        for (int mt = 0; mt < 4; ++mt)
            d[mt] = __builtin_amdgcn_mfma_f32_16x16x32_bf16(w1f[mt], bR, zero, 0, 0, 0);

        #pragma unroll
        for (int mt = 0; mt < 4; ++mt) {
            uint2 val = {cvt_pk(silu_f(d[mt][0]), silu_f(d[mt][1])),
                         cvt_pk(silu_f(d[mt][2]), silu_f(d[mt][3]))};
            int slot = mt * 2 + (hi >> 1);
            *(uint2*)(myB + n * 128 + ((slot ^ n7) << 4) + (hi & 1) * 8) = val;
        }
        s16x8 b0 = *(const s16x8*)(myB + n * 128 + ((hi ^ n7) << 4));
        s16x8 b1 = *(const s16x8*)(myB + n * 128 + (((4 + hi) ^ n7) << 4));

        // L2
        #pragma unroll
        for (int mt = 0; mt < 4; ++mt) {
            d[mt] = __builtin_amdgcn_mfma_f32_16x16x32_bf16(w2f[mt][0], b0, zero, 0, 0, 0);
            d[mt] = __builtin_amdgcn_mfma_f32_16x16x32_bf16(w2f[mt][1], b1, d[mt], 0, 0, 0);
        }
        #pragma unroll
        for (int mt = 0; mt < 4; ++mt) {
            uint2 val = {cvt_pk(silu_f(d[mt][0]), silu_f(d[mt][1])),
                         cvt_pk(silu_f(d[mt][2]), silu_f(d[mt][3]))};
            int slot = mt * 2 + (hi >> 1);
            *(uint2*)(myB + n * 128 + ((slot ^ n7) << 4) + (hi & 1) * 8) = val;
        }
        b0 = *(const s16x8*)(myB + n * 128 + ((hi ^ n7) << 4));
        b1 = *(const s16x8*)(myB + n * 128 + (((4 + hi) ^ n7) << 4));

        // L3
        #pragma unroll
        for (int mt = 0; mt < 4; ++mt) {
            d[mt] = __builtin_amdgcn_mfma_f32_16x16x32_bf16(w3f[mt][0], b0, zero, 0, 0, 0);
            d[mt] = __builtin_amdgcn_mfma_f32_16x16x32_bf16(w3f[mt][1], b1, d[mt], 0, 0, 0);
        }
        #pragma unroll
        for (int mt = 0; mt < 4; ++mt) {
            uint2 val = {cvt_pk(silu_f(d[mt][0]), silu_f(d[mt][1])),
                         cvt_pk(silu_f(d[mt][2]), silu_f(d[mt][3]))};
            int slot = mt * 2 + (hi >> 1);
            *(uint2*)(myB + n * 128 + ((slot ^ n7) << 4) + (hi & 1) * 8) = val;
        }
        b0 = *(const s16x8*)(myB + n * 128 + ((hi ^ n7) << 4));
        b1 = *(const s16x8*)(myB + n * 128 + (((4 + hi) ^ n7) << 4));

        // L4: 128 outputs (l=0,1), A from LDS sW4; pack (l0,l1) pairs per channel.
        f32x4 o[8];
        #pragma unroll
        for (int mt = 0; mt < 8; ++mt) {
            int row = mt * 16 + n, r7 = row & 7;
            s16x8 a0f = *(const s16x8*)(sW4 + row * 64 + ((hi ^ r7) << 3));
            s16x8 a1f = *(const s16x8*)(sW4 + row * 64 + (((4 + hi) ^ r7) << 3));
            o[mt] = __builtin_amdgcn_mfma_f32_16x16x32_bf16(a0f, b0, zero, 0, 0, 0);
            o[mt] = __builtin_amdgcn_mfma_f32_16x16x32_bf16(a1f, b1, o[mt], 0, 0, 0);
        }
        if ((base + n) < E) {
            size_t rowbase = (size_t)(base + n) * 64;
            #pragma unroll
            for (int mt = 0; mt < 4; ++mt) {
                uint4 val;
                val.x = cvt_pk(o[mt][0], o[mt + 4][0]);
                val.y = cvt_pk(o[mt][1], o[mt + 4][1]);
                val.z = cvt_pk(o[mt][2], o[mt + 4][2]);
                val.w = cvt_pk(o[mt][3], o[mt + 4][3]);
                *(uint4*)(tpw32 + rowbase + mt * 16 + hi * 4) = val;
            }
        }
    }
}

// K6a: CSR aggregation. Wave per node, lane = channel. 4-edge batched loads:
// issue 12 independent loads (t,x,ang ×4) then consume — hides L2 latency.
__global__ __launch_bounds__(256) void agg_kernel(const float4* __restrict__ csr_ang,
                                                  const int* __restrict__ csr_sender,
                                                  const unsigned* __restrict__ tpw32,
                                                  const int* __restrict__ offsets,
                                                  const ushort* __restrict__ x_ws,
                                                  ushort* __restrict__ agg, int N) {
    int wave = threadIdx.x >> 6, lane = threadIdx.x & 63;
    int node = blockIdx.x * 4 + wave;
    if (node >= N) return;
    int beg = offsets[node], end = offsets[node + 1];
    float a0 = 0, a1 = 0, a2 = 0, a3 = 0;
    for (int cb = beg; cb < end; cb += 64) {
        int m = min(64, end - cb);
        int sv = csr_sender[cb + min(lane, m - 1)];
        for (int e0 = 0; e0 < m; e0 += 4) {
            unsigned t[4];
            ushort x[4];
            float4 g[4];
            #pragma unroll
            for (int j = 0; j < 4; ++j) {
                int e = e0 + j;
                int ec = min(e, m - 1);
                t[j] = tpw32[(size_t)(cb + ec) * 64 + lane];
                x[j] = x_ws[(size_t)__shfl(sv, ec) * 64 + lane];
                if (e < m) g[j] = csr_ang[cb + e];
                else g[j] = make_float4(0.f, 0.f, 0.f, 0.f);
            }
            #pragma unroll
            for (int j = 0; j < 4; ++j) {
                float xv = bf2f(x[j]);
                float tp0 = u2f(t[j] << 16);
                float tp1 = u2f(t[j] & 0xffff0000u);
                float y0 = xv * tp0, y1 = xv * tp1;
                a0 += g[j].x * y0;
                a1 += g[j].y * y1;
                a2 += g[j].z * y1;
                a3 += g[j].w * y1;
            }
        }
    }
    size_t b = (size_t)node * 256 + lane;
    agg[b] = f2bf(a0 * 0.1f);
    agg[b + 64] = f2bf(a1 * 0.1f);
    agg[b + 128] = f2bf(a2 * 0.1f);
    agg[b + 192] = f2bf(a3 * 0.1f);
}

// K6b: per-32-node tile: feats = agg@W_lin (MFMA), scale by wn, out = f@W_p (+sc0).
__global__ __launch_bounds__(256) void node_out2_kernel(
    const float* __restrict__ nf, const float* __restrict__ one_hot,
    const ushort* __restrict__ wimg, const float* __restrict__ W_c0,
    const float* __restrict__ W_c1, const ushort* __restrict__ agg,
    float* __restrict__ out) {
    __shared__ __align__(16) ushort sWl[2 * 64 * 72];
    __shared__ __align__(16) ushort sF[4][32 * 72];
    __shared__ float sSc[32][64];
    __shared__ float sWc[2][640];
    __shared__ int sElem[32];
    int tid = threadIdx.x;
    int n0 = blockIdx.x * 32;
    int lane = tid & 63, m = tid >> 6;
    int lsel = (m == 0) ? 0 : 1;

    // direct-from-global W_p B-fragments (L2-resident image)
    s16x8 pf[4][2];
    #pragma unroll
    for (int nt = 0; nt < 4; ++nt)
        #pragma unroll
        for (int ks = 0; ks < 2; ++ks)
            pf[nt][ks] = *(const s16x8*)(wimg + 29696 +
                (lsel * 64 + nt * 16 + (lane & 15)) * 72 + ks * 32 + (lane >> 4) * 8);

    for (int i = tid; i < 1152; i += 256)
        ((s16x8*)sWl)[i] = ((const s16x8*)(wimg + 20480))[i];
    for (int i = tid; i < 1280; i += 256)
        sWc[i >= 640][i % 640] = (i >= 640 ? W_c1 : W_c0)[i % 640];
    if (tid < 32) {
        int nn = n0 + tid, e = 0;
        for (int a = 0; a < 10; ++a)
            if (one_hot[(size_t)nn * 10 + a] > 0.5f) { e = a; break; }
        sElem[tid] = e;
    }
    __syncthreads();

    // sc0 skip connection: 8 threads per node, 8 k's per thread, bf16 W_skip
    {
        int nl = tid >> 3, k0 = (tid & 7) * 8;
        int nn = n0 + nl, elem = sElem[nl];
        float acc[8] = {0, 0, 0, 0, 0, 0, 0, 0};
        const ushort* wskb = wimg + 38912;
        for (int c = 0; c < 64; ++c) {
            float v = nf[(size_t)nn * 64 + c];
            s16x8 w = *(const s16x8*)(wskb + ((size_t)c * 10 + elem) * 64 + k0);
            #pragma unroll
            for (int j = 0; j < 8; ++j) acc[j] += v * bf2f((ushort)w[j]);
        }
        #pragma unroll
        for (int j = 0; j < 8; ++j) sSc[nl][k0 + j] = acc[j];
    }

    // GEMM1: feats[m] = agg[:,m,:] @ W_lin[lsel]   (M=32, K=64, N=64)
    f32x4 acc[2][4] = {};
    s16x8 afr[2][2];
    #pragma unroll
    for (int mt = 0; mt < 2; ++mt)
        #pragma unroll
        for (int ks = 0; ks < 2; ++ks)
            afr[mt][ks] = *(const s16x8*)(agg +
                (((size_t)(n0 + mt * 16 + (lane & 15))) * 4 + m) * 64 +
                ks * 32 + (lane >> 4) * 8);
    #pragma unroll
    for (int nt = 0; nt < 4; ++nt)
        #pragma unroll
        for (int ks = 0; ks < 2; ++ks) {
            s16x8 b = *(const s16x8*)(sWl + (lsel * 64 + nt * 16 + (lane & 15)) * 72 +
                                      ks * 32 + (lane >> 4) * 8);
            #pragma unroll
            for (int mt = 0; mt < 2; ++mt)
                acc[mt][nt] = __builtin_amdgcn_mfma_f32_16x16x32_bf16(afr[mt][ks], b,
                                                                      acc[mt][nt], 0, 0, 0);
        }

    // scale by wn and write bf16 to sF
    #pragma unroll
    for (int mt = 0; mt < 2; ++mt)
        #pragma unroll
        for (int nt = 0; nt < 4; ++nt)
            #pragma unroll
            for (int r = 0; r < 4; ++r) {
                int nl = mt * 16 + (lane >> 4) * 4 + r;
                int k = nt * 16 + (lane & 15);
                float scale = sWc[lsel][sElem[nl] * 64 + k];
                sF[m][nl * 72 + k] = f2bf(acc[mt][nt][r] * scale);
            }
    __syncthreads();

    // GEMM2: out_m = f[m] @ W_p{0|1}
    f32x4 acc2[2][4] = {};
    s16x8 af2[2][2];
    #pragma unroll
    for (int mt = 0; mt < 2; ++mt)
        #pragma unroll
        for (int ks = 0; ks < 2; ++ks)
            af2[mt][ks] = *(const s16x8*)(&sF[m][(mt * 16 + (lane & 15)) * 72 +
                                                 ks * 32 + (lane >> 4) * 8]);
    #pragma unroll
    for (int nt = 0; nt < 4; ++nt)
        #pragma unroll
        for (int ks = 0; ks < 2; ++ks) {
            #pragma unroll
            for (int mt = 0; mt < 2; ++mt)
                acc2[mt][nt] = __builtin_amdgcn_mfma_f32_16x16x32_bf16(af2[mt][ks],
                                                                       pf[nt][ks],
                                                                       acc2[mt][nt], 0, 0, 0);
        }

    // epilogue
    #pragma unroll
    for (int mt = 0; mt < 2; ++mt)
        #pragma unroll
        for (int nt = 0; nt < 4; ++nt)
            #pragma unroll
            for (int r = 0; r < 4; ++r) {
                int nl = mt * 16 + (lane >> 4) * 4 + r;
                int k = nt * 16 + (lane & 15);
                size_t nn = (size_t)n0 + nl;
                if (m == 0)
                    out[nn * 256 + k] = acc2[mt][nt][r] + sSc[nl][k];
                else
                    out[nn * 256 + 64 + k * 3 + (m - 1)] = acc2[mt][nt][r];
            }
}

extern "C" void kernel_launch(void* const* d_in, const int* in_sizes, int n_in,
                              void* d_out, int out_size, void* d_ws, size_t ws_size,
                              hipStream_t stream) {
    const float* node_features = (const float*)d_in[0];
    const float* one_hot = (const float*)d_in[1];
    const float* angular = (const float*)d_in[2];
    const float* radial = (const float*)d_in[3];
    const float* W_up = (const float*)d_in[4];
    const float* W_mlp1 = (const float*)d_in[5];
    const float* W_mlp2 = (const float*)d_in[6];
    const float* W_mlp3 = (const float*)d_in[7];
    const float* W_mlp4 = (const float*)d_in[8];
    const float* W_lin = (const float*)d_in[9];
    const float* W_skip = (const float*)d_in[10];
    const float* W_c0 = (const float*)d_in[11];
    const float* W_c1 = (const float*)d_in[12];
    const float* W_p0 = (const float*)d_in[13];
    const float* W_p1 = (const float*)d_in[14];
    const int* edge_index = (const int*)d_in[15];
    float* out = (float*)d_out;

    int N = in_sizes[0] / 64;
    int E = in_sizes[2] / 16;
    const int* sender = edge_index;
    const int* receiver = edge_index + E;

    char* p = (char*)d_ws;
    ushort* x_ws = (ushort*)p;      p += (size_t)N * 64 * 2;
    unsigned* tpw32 = (unsigned*)p; p += (size_t)E * 64 * 4;
    ushort* agg = (ushort*)p;       p += (size_t)N * 256 * 2;
    ushort* wimg = (ushort*)p;      p += 79872 * 2;
    float4* csr_ang = (float4*)p;   p += (size_t)E * 16;
    ushort* csr_radb = (ushort*)p;  p += (size_t)E * 8 * 2;
    int* counts = (int*)p;          p += (size_t)N * 4;
    int* offsets = (int*)p;         p += (size_t)(N + 1) * 4;
    int* cursor = (int*)p;          p += (size_t)N * 4;
    int* csr_sender = (int*)p;      p += (size_t)E * 4;

    prep_up_kernel<<<N / 32 + 312, 256, 0, stream>>>(node_features, W_up, x_ws,
                                                     W_mlp1, W_mlp2, W_mlp3, W_mlp4,
                                                     W_lin, W_p0, W_p1, W_skip, wimg,
                                                     counts, N);
    hist_kernel<<<(E + 255) / 256, 256, 0, stream>>>(receiver, counts, E);
    scan_kernel<<<1, 1024, 0, stream>>>(counts, offsets, cursor, N);
    scatter_kernel<<<(E + 255) / 256, 256, 0, stream>>>(receiver, sender, angular,
                                                        radial, cursor, csr_sender,
                                                        csr_ang, csr_radb, E);
    edge_mlp_kernel<<<(E + 127) / 128, 256, 0, stream>>>(csr_radb, wimg, tpw32, E);
    agg_kernel<<<(N + 3) / 4, 256, 0, stream>>>(csr_ang, csr_sender, tpw32, offsets,
                                                x_ws, agg, N);
    node_out2_kernel<<<N / 32, 256, 0, stream>>>(node_features, one_hot, wimg,
                                                 W_c0, W_c1, agg, out);
}

// Round 10
// 117.575 us; speedup vs baseline: 1.7695x; 1.1022x over previous
//
#include <hip/hip_runtime.h>

typedef __attribute__((ext_vector_type(8))) short s16x8;
typedef __attribute__((ext_vector_type(4))) float f32x4;

__device__ inline float bf2f(ushort u) {
    union { unsigned int i; float f; } v; v.i = ((unsigned)u) << 16; return v.f;
}
__device__ inline float u2f(unsigned u) {
    union { unsigned int i; float f; } v; v.i = u; return v.f;
}
__device__ inline ushort f2bf(float f) {
    union { float f; unsigned int i; } v; v.f = f;
    unsigned r = v.i + 0x7FFFu + ((v.i >> 16) & 1u);
    return (ushort)(r >> 16);
}
__device__ inline unsigned cvt_pk(float lo, float hi) {
    unsigned d;
    asm("v_cvt_pk_bf16_f32 %0, %1, %2" : "=v"(d) : "v"(lo), "v"(hi));
    return d;
}
// fast silu: x * rcp(1 + 2^(-x*log2e)) — 5 VALU ops, correct at +-inf
__device__ inline float silu_f(float x) {
    float e;
    asm("v_exp_f32 %0, %1" : "=v"(e) : "v"(x * -1.44269504f));
    float d = 1.f + e, r;
    asm("v_rcp_f32 %0, %1" : "=v"(r) : "v"(d));
    return x * r;
}

// K1 merged: blocks [0, N/32) do node_up (32 nodes/block); rest do prep+counts.
// wimg ushort layout:
//   [0,4096)       W1t  (64m x 64k, k<8 real else 0), A-side swizzle
//   [4096,8192)    W2t  (64 x 64)
//   [8192,12288)   W3t  (64 x 64)
//   [12288,20480)  W4t  (128m x 64k)
//   [20480,29696)  wl_img: (l*64+col)*72 + c  = W_lin[l][c][col]
//   [29696,38912)  wp_img: (l*64+col)*72 + c  = W_p{l}[c][col]
//   [38912,79872)  wskb: W_skip bf16 linear (c*10+a)*64+k
__global__ __launch_bounds__(256) void prep_up_kernel(
    const float* __restrict__ nf, const float* __restrict__ W_up,
    ushort* __restrict__ x_ws,
    const float* __restrict__ W1, const float* __restrict__ W2,
    const float* __restrict__ W3, const float* __restrict__ W4,
    const float* __restrict__ W_lin, const float* __restrict__ Wp0,
    const float* __restrict__ Wp1, const float* __restrict__ W_skip,
    ushort* __restrict__ wimg, int* __restrict__ counts, int N) {
    __shared__ float sW[64 * 64];
    __shared__ float sNf[32][64];
    int tid = threadIdx.x;
    int nub = N / 32;
    if ((int)blockIdx.x < nub) {
        size_t n0 = (size_t)blockIdx.x * 32;
        for (int i = tid; i < 4096; i += 256) sW[i] = W_up[i];
        for (int i = tid; i < 2048; i += 256) {
            int r = i >> 6, c = i & 63;
            sNf[r][c] = nf[(n0 + r) * 64 + c];
        }
        __syncthreads();
        int r = tid >> 3, k0 = (tid & 7) * 8;
        float acc[8] = {0, 0, 0, 0, 0, 0, 0, 0};
        #pragma unroll 4
        for (int c = 0; c < 64; ++c) {
            float v = sNf[r][c];
            const float* wr = &sW[c * 64 + k0];
            #pragma unroll
            for (int j = 0; j < 8; ++j) acc[j] += v * wr[j];
        }
        uint4 val;
        val.x = cvt_pk(acc[0], acc[1]);
        val.y = cvt_pk(acc[2], acc[3]);
        val.z = cvt_pk(acc[4], acc[5]);
        val.w = cvt_pk(acc[6], acc[7]);
        *(uint4*)(x_ws + (n0 + r) * 64 + k0) = val;
        return;
    }
    int idx = ((int)blockIdx.x - nub) * 256 + tid;
    if (idx < N) counts[idx] = 0;
    if (idx < 4096) {
        int m = idx >> 6, k = idx & 63;
        int dst = m * 64 + ((((k >> 3) ^ (m & 7))) << 3) + (k & 7);
        wimg[dst] = (k < 8) ? f2bf(W1[k * 64 + m]) : (ushort)0;
    } else if (idx < 8192) {
        int i = idx - 4096;
        int m = i >> 6, k = i & 63;
        int dst = 4096 + m * 64 + ((((k >> 3) ^ (m & 7))) << 3) + (k & 7);
        wimg[dst] = f2bf(W2[k * 64 + m]);
    } else if (idx < 12288) {
        int i = idx - 8192;
        int m = i >> 6, k = i & 63;
        int dst = 8192 + m * 64 + ((((k >> 3) ^ (m & 7))) << 3) + (k & 7);
        wimg[dst] = f2bf(W3[k * 64 + m]);
    } else if (idx < 20480) {
        int i = idx - 12288;
        int m = i >> 6, k = i & 63;  // m in 0..127
        int dst = 12288 + m * 64 + ((((k >> 3) ^ (m & 7))) << 3) + (k & 7);
        wimg[dst] = f2bf(W4[k * 256 + m]);
    } else if (idx < 29696) {
        int i = idx - 20480;
        int row = i / 72, k = i % 72;
        int l = row >> 6, col = row & 63;
        wimg[idx] = (k < 64) ? f2bf(W_lin[l * 4096 + k * 64 + col]) : (ushort)0;
    } else if (idx < 38912) {
        int i = idx - 29696;
        int row = i / 72, k = i % 72;
        int l = row >> 6, col = row & 63;
        const float* Wp = l ? Wp1 : Wp0;
        wimg[idx] = (k < 64) ? f2bf(Wp[k * 64 + col]) : (ushort)0;
    } else if (idx < 79872) {
        int i = idx - 38912;
        wimg[idx] = f2bf(W_skip[i]);
    }
}

// K2: histogram of receivers
__global__ __launch_bounds__(256) void hist_kernel(const int* __restrict__ recv,
                                                   int* __restrict__ counts, int E) {
    int e = blockIdx.x * 256 + threadIdx.x;
    if (e < E) atomicAdd(&counts[recv[e]], 1);
}

// K3: single-pass chunked exclusive scan counts -> offsets (and cursor copy)
__global__ __launch_bounds__(1024) void scan_kernel(const int* __restrict__ counts,
                                                    int* __restrict__ offsets,
                                                    int* __restrict__ cursor, int n) {
    __shared__ int wsums[16];
    int tid = threadIdx.x, lane = tid & 63, wid = tid >> 6;
    int CH = (n + 1023) >> 10;
    int base = tid * CH;
    int cnt[20];
    int tot = 0;
    if (CH <= 20) {
        #pragma unroll
        for (int j = 0; j < 20; ++j) {
            int i = base + j;
            cnt[j] = (j < CH && i < n) ? counts[i] : 0;
            tot += cnt[j];
        }
    } else {
        for (int j = 0; j < CH; ++j) {
            int i = base + j;
            if (i < n) tot += counts[i];
        }
    }
    int v = tot;
    for (int off = 1; off < 64; off <<= 1) {
        int t = __shfl_up(v, off, 64);
        if (lane >= off) v += t;
    }
    if (lane == 63) wsums[wid] = v;
    __syncthreads();
    if (tid == 0) {
        int acc = 0;
        for (int w = 0; w < 16; ++w) { int t = wsums[w]; wsums[w] = acc; acc += t; }
    }
    __syncthreads();
    int excl = wsums[wid] + v - tot;
    if (CH <= 20) {
        #pragma unroll
        for (int j = 0; j < 20; ++j) {
            int i = base + j;
            if (j < CH && i < n) {
                offsets[i] = excl; cursor[i] = excl; excl += cnt[j];
            }
        }
    } else {
        for (int j = 0; j < CH; ++j) {
            int i = base + j;
            if (i < n) { offsets[i] = excl; cursor[i] = excl; excl += counts[i]; }
        }
    }
    if (tid == 1023) offsets[n] = excl;
}

// K5 (fused): edge MLP in ORIGINAL edge order + CSR scatter of all outputs.
// 128 edges/block, wave owns 32 edges (2 subpasses of 16). hi==0 lanes claim
// CSR positions via atomicAdd and write csr_sender/csr_ang; L4 output lands at
// tpw32[pos] (uint32-packed l0|l1<<16 per channel).
__global__ __launch_bounds__(256) void edge_mlp_kernel(
    const int* __restrict__ recv, const int* __restrict__ sender,
    const float* __restrict__ angular, const float* __restrict__ radial,
    int* __restrict__ cursor, int* __restrict__ csr_sender,
    float4* __restrict__ csr_ang, const ushort* __restrict__ wimg,
    unsigned* __restrict__ tpw32, int E) {
    __shared__ __align__(16) ushort sW4[8192];       // 16KB
    __shared__ __align__(16) ushort sB[4][1024];     // per-wave h bounce, 2KB each
    int tid = threadIdx.x, lane = tid & 63, wave = tid >> 6;
    int n = lane & 15, hi = lane >> 4;

    for (int i = tid; i < 1024; i += 256)
        ((s16x8*)sW4)[i] = ((const s16x8*)(wimg + 12288))[i];

    // preload A-side weight fragments (VGPR-resident, block-invariant)
    s16x8 w1f[4], w2f[4][2], w3f[4][2];
    #pragma unroll
    for (int mt = 0; mt < 4; ++mt) {
        int row = mt * 16 + n, r7 = row & 7;
        w1f[mt] = *(const s16x8*)(wimg + row * 64 + ((hi ^ r7) << 3));
        #pragma unroll
        for (int ks = 0; ks < 2; ++ks) {
            w2f[mt][ks] = *(const s16x8*)(wimg + 4096 + row * 64 + (((ks * 4 + hi) ^ r7) << 3));
            w3f[mt][ks] = *(const s16x8*)(wimg + 8192 + row * 64 + (((ks * 4 + hi) ^ r7) << 3));
        }
    }
    __syncthreads();

    char* myB = (char*)sB[wave];
    int n7 = n & 7;

    for (int sub = 0; sub < 2; ++sub) {
        int base = blockIdx.x * 128 + wave * 32 + sub * 16;
        if (base >= E) break;
        int e = base + n;
        bool oke = e < E;
        int eC = min(e, E - 1);

        // radial B-fragment packed in-register (k = hi*8+j; only k<8 real)
        // + CSR position claim (hi==0 lanes only)
        s16x8 bR;
        #pragma unroll
        for (int j = 0; j < 8; ++j) bR[j] = 0;
        int pos = 0;
        if (hi == 0) {
            float4 r0 = *(const float4*)(radial + (size_t)eC * 8);
            float4 r1 = *(const float4*)(radial + (size_t)eC * 8 + 4);
            union { s16x8 v; uint4 u; } bb;
            bb.u.x = cvt_pk(r0.x, r0.y);
            bb.u.y = cvt_pk(r0.z, r0.w);
            bb.u.z = cvt_pk(r1.x, r1.y);
            bb.u.w = cvt_pk(r1.z, r1.w);
            bR = bb.v;
            if (oke) {
                int r = recv[e];
                pos = atomicAdd(&cursor[r], 1);
                csr_sender[pos] = sender[e];
                csr_ang[pos] = *(const float4*)(angular + (size_t)e * 16);
            }
        }
        pos = __shfl(pos, n);  // broadcast this edge's CSR position to all hi

        f32x4 zero = {0.f, 0.f, 0.f, 0.f};
        f32x4 d[4];
        // L1 (K=32, zero-padded)
        #pragma unroll
        for (int mt = 0; mt < 4; ++mt)
            d[mt] = __builtin_amdgcn_mfma_f32_16x16x32_bf16(w1f[mt], bR, zero, 0, 0, 0);

        #pragma unroll
        for (int mt = 0; mt < 4; ++mt) {
            uint2 val = {cvt_pk(silu_f(d[mt][0]), silu_f(d[mt][1])),
                         cvt_pk(silu_f(d[mt][2]), silu_f(d[mt][3]))};
            int slot = mt * 2 + (hi >> 1);
            *(uint2*)(myB + n * 128 + ((slot ^ n7) << 4) + (hi & 1) * 8) = val;
        }
        s16x8 b0 = *(const s16x8*)(myB + n * 128 + ((hi ^ n7) << 4));
        s16x8 b1 = *(const s16x8*)(myB + n * 128 + (((4 + hi) ^ n7) << 4));

        // L2
        #pragma unroll
        for (int mt = 0; mt < 4; ++mt) {
            d[mt] = __builtin_amdgcn_mfma_f32_16x16x32_bf16(w2f[mt][0], b0, zero, 0, 0, 0);
            d[mt] = __builtin_amdgcn_mfma_f32_16x16x32_bf16(w2f[mt][1], b1, d[mt], 0, 0, 0);
        }
        #pragma unroll
        for (int mt = 0; mt < 4; ++mt) {
            uint2 val = {cvt_pk(silu_f(d[mt][0]), silu_f(d[mt][1])),
                         cvt_pk(silu_f(d[mt][2]), silu_f(d[mt][3]))};
            int slot = mt * 2 + (hi >> 1);
            *(uint2*)(myB + n * 128 + ((slot ^ n7) << 4) + (hi & 1) * 8) = val;
        }
        b0 = *(const s16x8*)(myB + n * 128 + ((hi ^ n7) << 4));
        b1 = *(const s16x8*)(myB + n * 128 + (((4 + hi) ^ n7) << 4));

        // L3
        #pragma unroll
        for (int mt = 0; mt < 4; ++mt) {
            d[mt] = __builtin_amdgcn_mfma_f32_16x16x32_bf16(w3f[mt][0], b0, zero, 0, 0, 0);
            d[mt] = __builtin_amdgcn_mfma_f32_16x16x32_bf16(w3f[mt][1], b1, d[mt], 0, 0, 0);
        }
        #pragma unroll
        for (int mt = 0; mt < 4; ++mt) {
            uint2 val = {cvt_pk(silu_f(d[mt][0]), silu_f(d[mt][1])),
                         cvt_pk(silu_f(d[mt][2]), silu_f(d[mt][3]))};
            int slot = mt * 2 + (hi >> 1);
            *(uint2*)(myB + n * 128 + ((slot ^ n7) << 4) + (hi & 1) * 8) = val;
        }
        b0 = *(const s16x8*)(myB + n * 128 + ((hi ^ n7) << 4));
        b1 = *(const s16x8*)(myB + n * 128 + (((4 + hi) ^ n7) << 4));

        // L4: 128 outputs (l=0,1), A from LDS sW4; pack (l0,l1) pairs per channel
        // and scatter to CSR row `pos`.
        f32x4 o[8];
        #pragma unroll
        for (int mt = 0; mt < 8; ++mt) {
            int row = mt * 16 + n, r7 = row & 7;
            s16x8 a0f = *(const s16x8*)(sW4 + row * 64 + ((hi ^ r7) << 3));
            s16x8 a1f = *(const s16x8*)(sW4 + row * 64 + (((4 + hi) ^ r7) << 3));
            o[mt] = __builtin_amdgcn_mfma_f32_16x16x32_bf16(a0f, b0, zero, 0, 0, 0);
            o[mt] = __builtin_amdgcn_mfma_f32_16x16x32_bf16(a1f, b1, o[mt], 0, 0, 0);
        }
        if (oke) {
            size_t rowbase = (size_t)pos * 64;
            #pragma unroll
            for (int mt = 0; mt < 4; ++mt) {
                uint4 val;
                val.x = cvt_pk(o[mt][0], o[mt + 4][0]);
                val.y = cvt_pk(o[mt][1], o[mt + 4][1]);
                val.z = cvt_pk(o[mt][2], o[mt + 4][2]);
                val.w = cvt_pk(o[mt][3], o[mt + 4][3]);
                *(uint4*)(tpw32 + rowbase + mt * 16 + hi * 4) = val;
            }
        }
    }
}

// K6a: CSR aggregation. Wave per node, lane = channel. 4-edge batched loads:
// issue 12 independent loads (t,x,ang ×4) then consume — hides L2 latency.
__global__ __launch_bounds__(256) void agg_kernel(const float4* __restrict__ csr_ang,
                                                  const int* __restrict__ csr_sender,
                                                  const unsigned* __restrict__ tpw32,
                                                  const int* __restrict__ offsets,
                                                  const ushort* __restrict__ x_ws,
                                                  ushort* __restrict__ agg, int N) {
    int wave = threadIdx.x >> 6, lane = threadIdx.x & 63;
    int node = blockIdx.x * 4 + wave;
    if (node >= N) return;
    int beg = offsets[node], end = offsets[node + 1];
    float a0 = 0, a1 = 0, a2 = 0, a3 = 0;
    for (int cb = beg; cb < end; cb += 64) {
        int m = min(64, end - cb);
        int sv = csr_sender[cb + min(lane, m - 1)];
        for (int e0 = 0; e0 < m; e0 += 4) {
            unsigned t[4];
            ushort x[4];
            float4 g[4];
            #pragma unroll
            for (int j = 0; j < 4; ++j) {
                int e = e0 + j;
                int ec = min(e, m - 1);
                t[j] = tpw32[(size_t)(cb + ec) * 64 + lane];
                x[j] = x_ws[(size_t)__shfl(sv, ec) * 64 + lane];
                if (e < m) g[j] = csr_ang[cb + e];
                else g[j] = make_float4(0.f, 0.f, 0.f, 0.f);
            }
            #pragma unroll
            for (int j = 0; j < 4; ++j) {
                float xv = bf2f(x[j]);
                float tp0 = u2f(t[j] << 16);
                float tp1 = u2f(t[j] & 0xffff0000u);
                float y0 = xv * tp0, y1 = xv * tp1;
                a0 += g[j].x * y0;
                a1 += g[j].y * y1;
                a2 += g[j].z * y1;
                a3 += g[j].w * y1;
            }
        }
    }
    size_t b = (size_t)node * 256 + lane;
    agg[b] = f2bf(a0 * 0.1f);
    agg[b + 64] = f2bf(a1 * 0.1f);
    agg[b + 128] = f2bf(a2 * 0.1f);
    agg[b + 192] = f2bf(a3 * 0.1f);
}

// K6b: per-32-node tile: feats = agg@W_lin (MFMA), scale by wn, out = f@W_p (+sc0).
__global__ __launch_bounds__(256) void node_out2_kernel(
    const float* __restrict__ nf, const float* __restrict__ one_hot,
    const ushort* __restrict__ wimg, const float* __restrict__ W_c0,
    const float* __restrict__ W_c1, const ushort* __restrict__ agg,
    float* __restrict__ out) {
    __shared__ __align__(16) ushort sWl[2 * 64 * 72];
    __shared__ __align__(16) ushort sF[4][32 * 72];
    __shared__ float sSc[32][64];
    __shared__ float sWc[2][640];
    __shared__ int sElem[32];
    int tid = threadIdx.x;
    int n0 = blockIdx.x * 32;
    int lane = tid & 63, m = tid >> 6;
    int lsel = (m == 0) ? 0 : 1;

    // direct-from-global W_p B-fragments (L2-resident image)
    s16x8 pf[4][2];
    #pragma unroll
    for (int nt = 0; nt < 4; ++nt)
        #pragma unroll
        for (int ks = 0; ks < 2; ++ks)
            pf[nt][ks] = *(const s16x8*)(wimg + 29696 +
                (lsel * 64 + nt * 16 + (lane & 15)) * 72 + ks * 32 + (lane >> 4) * 8);

    for (int i = tid; i < 1152; i += 256)
        ((s16x8*)sWl)[i] = ((const s16x8*)(wimg + 20480))[i];
    for (int i = tid; i < 1280; i += 256)
        sWc[i >= 640][i % 640] = (i >= 640 ? W_c1 : W_c0)[i % 640];
    if (tid < 32) {
        int nn = n0 + tid, e = 0;
        for (int a = 0; a < 10; ++a)
            if (one_hot[(size_t)nn * 10 + a] > 0.5f) { e = a; break; }
        sElem[tid] = e;
    }
    __syncthreads();

    // sc0 skip connection: 8 threads per node, 8 k's per thread, bf16 W_skip
    {
        int nl = tid >> 3, k0 = (tid & 7) * 8;
        int nn = n0 + nl, elem = sElem[nl];
        float acc[8] = {0, 0, 0, 0, 0, 0, 0, 0};
        const ushort* wskb = wimg + 38912;
        for (int c = 0; c < 64; ++c) {
            float v = nf[(size_t)nn * 64 + c];
            s16x8 w = *(const s16x8*)(wskb + ((size_t)c * 10 + elem) * 64 + k0);
            #pragma unroll
            for (int j = 0; j < 8; ++j) acc[j] += v * bf2f((ushort)w[j]);
        }
        #pragma unroll
        for (int j = 0; j < 8; ++j) sSc[nl][k0 + j] = acc[j];
    }

    // GEMM1: feats[m] = agg[:,m,:] @ W_lin[lsel]   (M=32, K=64, N=64)
    f32x4 acc[2][4] = {};
    s16x8 afr[2][2];
    #pragma unroll
    for (int mt = 0; mt < 2; ++mt)
        #pragma unroll
        for (int ks = 0; ks < 2; ++ks)
            afr[mt][ks] = *(const s16x8*)(agg +
                (((size_t)(n0 + mt * 16 + (lane & 15))) * 4 + m) * 64 +
                ks * 32 + (lane >> 4) * 8);
    #pragma unroll
    for (int nt = 0; nt < 4; ++nt)
        #pragma unroll
        for (int ks = 0; ks < 2; ++ks) {
            s16x8 b = *(const s16x8*)(sWl + (lsel * 64 + nt * 16 + (lane & 15)) * 72 +
                                      ks * 32 + (lane >> 4) * 8);
            #pragma unroll
            for (int mt = 0; mt < 2; ++mt)
                acc[mt][nt] = __builtin_amdgcn_mfma_f32_16x16x32_bf16(afr[mt][ks], b,
                                                                      acc[mt][nt], 0, 0, 0);
        }

    // scale by wn and write bf16 to sF
    #pragma unroll
    for (int mt = 0; mt < 2; ++mt)
        #pragma unroll
        for (int nt = 0; nt < 4; ++nt)
            #pragma unroll
            for (int r = 0; r < 4; ++r) {
                int nl = mt * 16 + (lane >> 4) * 4 + r;
                int k = nt * 16 + (lane & 15);
                float scale = sWc[lsel][sElem[nl] * 64 + k];
                sF[m][nl * 72 + k] = f2bf(acc[mt][nt][r] * scale);
            }
    __syncthreads();

    // GEMM2: out_m = f[m] @ W_p{0|1}
    f32x4 acc2[2][4] = {};
    s16x8 af2[2][2];
    #pragma unroll
    for (int mt = 0; mt < 2; ++mt)
        #pragma unroll
        for (int ks = 0; ks < 2; ++ks)
            af2[mt][ks] = *(const s16x8*)(&sF[m][(mt * 16 + (lane & 15)) * 72 +
                                                 ks * 32 + (lane >> 4) * 8]);
    #pragma unroll
    for (int nt = 0; nt < 4; ++nt)
        #pragma unroll
        for (int ks = 0; ks < 2; ++ks) {
            #pragma unroll
            for (int mt = 0; mt < 2; ++mt)
                acc2[mt][nt] = __builtin_amdgcn_mfma_f32_16x16x32_bf16(af2[mt][ks],
                                                                       pf[nt][ks],
                                                                       acc2[mt][nt], 0, 0, 0);
        }

    // epilogue
    #pragma unroll
    for (int mt = 0; mt < 2; ++mt)
        #pragma unroll
        for (int nt = 0; nt < 4; ++nt)
            #pragma unroll
            for (int r = 0; r < 4; ++r) {
                int nl = mt * 16 + (lane >> 4) * 4 + r;
                int k = nt * 16 + (lane & 15);
                size_t nn = (size_t)n0 + nl;
                if (m == 0)
                    out[nn * 256 + k] = acc2[mt][nt][r] + sSc[nl][k];
                else
                    out[nn * 256 + 64 + k * 3 + (m - 1)] = acc2[mt][nt][r];
            }
}

extern "C" void kernel_launch(void* const* d_in, const int* in_sizes, int n_in,
                              void* d_out, int out_size, void* d_ws, size_t ws_size,
                              hipStream_t stream) {
    const float* node_features = (const float*)d_in[0];
    const float* one_hot = (const float*)d_in[1];
    const float* angular = (const float*)d_in[2];
    const float* radial = (const float*)d_in[3];
    const float* W_up = (const float*)d_in[4];
    const float* W_mlp1 = (const float*)d_in[5];
    const float* W_mlp2 = (const float*)d_in[6];
    const float* W_mlp3 = (const float*)d_in[7];
    const float* W_mlp4 = (const float*)d_in[8];
    const float* W_lin = (const float*)d_in[9];
    const float* W_skip = (const float*)d_in[10];
    const float* W_c0 = (const float*)d_in[11];
    const float* W_c1 = (const float*)d_in[12];
    const float* W_p0 = (const float*)d_in[13];
    const float* W_p1 = (const float*)d_in[14];
    const int* edge_index = (const int*)d_in[15];
    float* out = (float*)d_out;

    int N = in_sizes[0] / 64;
    int E = in_sizes[2] / 16;
    const int* sender = edge_index;
    const int* receiver = edge_index + E;

    char* p = (char*)d_ws;
    ushort* x_ws = (ushort*)p;      p += (size_t)N * 64 * 2;
    unsigned* tpw32 = (unsigned*)p; p += (size_t)E * 64 * 4;
    ushort* agg = (ushort*)p;       p += (size_t)N * 256 * 2;
    ushort* wimg = (ushort*)p;      p += 79872 * 2;
    float4* csr_ang = (float4*)p;   p += (size_t)E * 16;
    int* counts = (int*)p;          p += (size_t)N * 4;
    int* offsets = (int*)p;         p += (size_t)(N + 1) * 4;
    int* cursor = (int*)p;          p += (size_t)N * 4;
    int* csr_sender = (int*)p;      p += (size_t)E * 4;

    prep_up_kernel<<<N / 32 + 312, 256, 0, stream>>>(node_features, W_up, x_ws,
                                                     W_mlp1, W_mlp2, W_mlp3, W_mlp4,
                                                     W_lin, W_p0, W_p1, W_skip, wimg,
                                                     counts, N);
    hist_kernel<<<(E + 255) / 256, 256, 0, stream>>>(receiver, counts, E);
    scan_kernel<<<1, 1024, 0, stream>>>(counts, offsets, cursor, N);
    edge_mlp_kernel<<<(E + 127) / 128, 256, 0, stream>>>(receiver, sender, angular,
                                                         radial, cursor, csr_sender,
                                                         csr_ang, wimg, tpw32, E);
    agg_kernel<<<(N + 3) / 4, 256, 0, stream>>>(csr_ang, csr_sender, tpw32, offsets,
                                                x_ws, agg, N);
    node_out2_kernel<<<N / 32, 256, 0, stream>>>(node_features, one_hot, wimg,
                                                 W_c0, W_c1, agg, out);
}